// Round 7
// baseline (1652.877 us; speedup 1.0000x reference)
//
#include <hip/hip_runtime.h>

#define B_ 256
#define S_ 80
#define H_ 512
#define V_ 4096
#define NSTEP 27

typedef unsigned short u16;
typedef __attribute__((ext_vector_type(8))) short short8v;
typedef __attribute__((ext_vector_type(4))) float f32x4;
typedef __attribute__((ext_vector_type(4))) unsigned short ushort4v;

#define MFMA_(a,b,c) __builtin_amdgcn_mfma_f32_16x16x32_bf16(a,b,c,0,0,0)
#define MFMA3(acc, ah, al, bh, bl) do{ acc = MFMA_(ah,bh,acc); acc = MFMA_(ah,bl,acc); acc = MFMA_(al,bh,acc);}while(0)

__device__ __forceinline__ unsigned fkey(float v){
    unsigned u = __float_as_uint(v);
    return (u & 0x80000000u) ? ~u : (u | 0x80000000u);
}
__device__ __forceinline__ u16 bf16_rne(float f){
    unsigned u = __float_as_uint(f);
    return (u16)((u + 0x7FFFu + ((u >> 16) & 1u)) >> 16);
}
__device__ __forceinline__ void split_f4(float4 v, ushort4v& hi, ushort4v& lo){
    float arr[4] = {v.x, v.y, v.z, v.w};
    ushort4v h, l;
#pragma unroll
    for (int i = 0; i < 4; ++i){
        u16 hb = bf16_rne(arr[i]);
        h[i] = hb;
        l[i] = bf16_rne(arr[i] - __uint_as_float(((unsigned)hb) << 16));
    }
    hi = h; lo = l;
}

// ---------------- front ----------------
__global__ __launch_bounds__(64) void matvec512(const float* __restrict__ W,
                                                const float* __restrict__ v,
                                                float* __restrict__ out){
    int row = blockIdx.x, lane = threadIdx.x;
    const float* wr = W + row * 512;
    float s = 0.f;
#pragma unroll
    for (int i = 0; i < 8; ++i) s += wr[lane + 64*i] * v[lane + 64*i];
#pragma unroll
    for (int off = 32; off; off >>= 1) s += __shfl_xor(s, off);
    if (lane == 0) out[row] = s;
}

__global__ __launch_bounds__(256) void score_kernel(const float* __restrict__ enc,
                                                    const float* __restrict__ weff,
                                                    float* __restrict__ scores){
    int wv = threadIdx.x >> 6, lane = threadIdx.x & 63;
    int p = blockIdx.x * 4 + wv;
    const float* e = enc + (size_t)p * 512;
    float s = 0.f;
#pragma unroll
    for (int i = 0; i < 8; ++i) s += e[lane + 64*i] * weff[lane + 64*i];
#pragma unroll
    for (int off = 32; off; off >>= 1) s += __shfl_xor(s, off);
    if (lane == 0) scores[p] = s;
}

__global__ __launch_bounds__(512) void softmax_ctx(const float* __restrict__ enc,
                                                   const float* __restrict__ scores,
                                                   float* __restrict__ ctx){
    __shared__ float att[S_];
    int b = blockIdx.x, tid = threadIdx.x;
    if (tid < S_) att[tid] = scores[b*S_ + tid];
    __syncthreads();
    if (tid == 0){
        float mx = att[0];
        for (int s = 1; s < S_; ++s) mx = fmaxf(mx, att[s]);
        float sum = 0.f;
        for (int s = 0; s < S_; ++s){ float e = expf(att[s] - mx); att[s] = e; sum += e; }
        float inv = 1.f / sum;
        for (int s = 0; s < S_; ++s) att[s] *= inv;
    }
    __syncthreads();
    float a = 0.f;
    const float* eb = enc + (size_t)b * (S_*H_);
    for (int s = 0; s < S_; ++s) a += att[s] * eb[s*H_ + tid];
    ctx[b*H_ + tid] = a;
}

template<int TM>
__global__ __launch_bounds__(256) void gemm_abt(const float* __restrict__ A, int lda,
                                                const float* __restrict__ Bm, int ldb,
                                                const float* __restrict__ bias,
                                                float* __restrict__ C, int ldc, int K){
    constexpr int RPT = TM / 16;
    __shared__ float As[16][TM + 4];
    __shared__ float Bs[16][64 + 4];
    int m0 = blockIdx.x * TM, n0 = blockIdx.y * 64;
    int tid = threadIdx.x;
    int lk = tid & 15, lr = tid >> 4;
    int tx = tid & 15, ty = tid >> 4;
    float c[RPT][4] = {};
    for (int k0 = 0; k0 < K; k0 += 16){
#pragma unroll
        for (int i = 0; i < RPT; ++i)
            As[lk][lr*RPT + i] = A[(size_t)(m0 + lr*RPT + i)*lda + k0 + lk];
#pragma unroll
        for (int i = 0; i < 4; ++i)
            Bs[lk][lr*4 + i] = Bm[(size_t)(n0 + lr*4 + i)*ldb + k0 + lk];
        __syncthreads();
#pragma unroll
        for (int k = 0; k < 16; ++k){
            float b4[4];
            *(float4*)b4 = *(const float4*)&Bs[k][tx*4];
#pragma unroll
            for (int i = 0; i < RPT; ++i){
                float a = As[k][ty*RPT + i];
#pragma unroll
                for (int j = 0; j < 4; ++j) c[i][j] += a * b4[j];
            }
        }
        __syncthreads();
    }
#pragma unroll
    for (int j = 0; j < 4; ++j){
        float bb = bias ? bias[n0 + tx*4 + j] : 0.f;
#pragma unroll
        for (int i = 0; i < RPT; ++i)
            C[(size_t)(m0 + ty*RPT + i)*ldc + n0 + tx*4 + j] = c[i][j] + bb;
    }
}

// ---------------- one-time transforms fused into a single kernel ----------------
__global__ __launch_bounds__(256) void prep_all(
    const float* __restrict__ Whh, const float* __restrict__ Wo,
    const float* __restrict__ emb, const float* __restrict__ Wih,
    const float* __restrict__ elhs,
    u16* __restrict__ WhhHi, u16* __restrict__ WhhLo,
    u16* __restrict__ WoThi, u16* __restrict__ WoTlo,
    u16* __restrict__ EmbHi, u16* __restrict__ EmbLo,
    u16* __restrict__ WihLHi, u16* __restrict__ WihLLo,
    u16* __restrict__ Sh, u16* __restrict__ Sl,
    unsigned* __restrict__ zp, int nz)
{
    __shared__ float T[64][65];
    int b = blockIdx.x, tid = threadIdx.x;
    if (b < 768){
        int idx = (b*256 + tid)*4;
        float4 v = *(const float4*)&Whh[idx];
        ushort4v h,l; split_f4(v,h,l);
        *(ushort4v*)&WhhHi[idx]=h; *(ushort4v*)&WhhLo[idx]=l;
    } else if (b < 1280){
        int lb = b - 768;
        int k0 = (lb & 7)*64, n0 = (lb >> 3)*64;
#pragma unroll
        for (int i = 0; i < 16; ++i){
            int idx = tid + i*256;
            int kk = idx >> 6, nn = idx & 63;
            T[kk][nn] = Wo[(size_t)(k0+kk)*4096 + n0+nn];
        }
        __syncthreads();
#pragma unroll
        for (int i = 0; i < 16; ++i){
            int idx = tid + i*256;
            int nn = idx >> 6, kk = idx & 63;
            float v = T[kk][nn];
            u16 hi = bf16_rne(v);
            u16 lo = bf16_rne(v - __uint_as_float(((unsigned)hi) << 16));
            size_t o = (size_t)(n0+nn)*512 + k0+kk;
            WoThi[o] = hi; WoTlo[o] = lo;
        }
    } else if (b < 5376){
        int idx = ((b-1280)*256 + tid)*4;
        float4 v = *(const float4*)&emb[idx];
        ushort4v h,l; split_f4(v,h,l);
        *(ushort4v*)&EmbHi[idx]=h; *(ushort4v*)&EmbLo[idx]=l;
    } else if (b < 6912){
        int id = ((b-5376)*256 + tid)*4;
        int r = id >> 10, c = id & 1023;
        float4 v = *(const float4*)&Wih[(size_t)r*1536 + c];
        ushort4v h,l; split_f4(v,h,l);
        *(ushort4v*)&WihLHi[id]=h; *(ushort4v*)&WihLLo[id]=l;
    } else if (b < 7040){
        int idx = ((b-6912)*256 + tid)*4;
        float4 v = *(const float4*)&elhs[idx];
        ushort4v h,l; split_f4(v,h,l);
        *(ushort4v*)&Sh[idx]=h; *(ushort4v*)&Sl[idx]=l;
    } else {
        int i = ((b-7040)*256 + tid)*4;
        if (i < nz){ zp[i]=0u; zp[i+1]=0u; zp[i+2]=0u; zp[i+3]=0u; }
    }
}

// ---------------- Eproj: emb(4096x1024) @ WihL^T(1536x1024) ----------------
// LDS pad 44 u16 (88B row stride, 22 banks) -> conflict-free fragment reads.
__global__ __launch_bounds__(256) void eproj_u16(const u16* __restrict__ Ahi, const u16* __restrict__ Alo,
                                                 const u16* __restrict__ Bhi, const u16* __restrict__ Blo,
                                                 float* __restrict__ C){
    __shared__ u16 Ah[64][44], Al[64][44], Bh[64][44], Bl[64][44];
    int n0 = blockIdx.x * 64, m0 = blockIdx.y * 64;
    int tid = threadIdx.x, lane = tid & 63, wid = tid >> 6;
    int wm = (wid & 1) * 32, wn = (wid >> 1) * 32;
    int l15 = lane & 15, lk = (lane >> 4) * 8;
    f32x4 acc[2][2] = {};
    short8v ra[2], rb[2];
#pragma unroll
    for (int j = 0; j < 2; ++j){
        int c = j*256 + tid;
        int half = c >> 8, i = c & 255, row = i >> 2, k8 = (i & 3)*8;
        ra[j] = *(const short8v*)&(half ? Alo : Ahi)[(size_t)(m0+row)*1024 + k8];
        rb[j] = *(const short8v*)&(half ? Blo : Bhi)[(size_t)(n0+row)*1024 + k8];
    }
    for (int k0 = 0; k0 < 1024; k0 += 32){
        __syncthreads();
#pragma unroll
        for (int j = 0; j < 2; ++j){
            int c = j*256 + tid;
            int half = c >> 8, i = c & 255, row = i >> 2, k8 = (i & 3)*8;
            if (half){ *(short8v*)&Al[row][k8] = ra[j]; *(short8v*)&Bl[row][k8] = rb[j]; }
            else     { *(short8v*)&Ah[row][k8] = ra[j]; *(short8v*)&Bh[row][k8] = rb[j]; }
        }
        __syncthreads();
        if (k0 + 32 < 1024){
#pragma unroll
            for (int j = 0; j < 2; ++j){
                int c = j*256 + tid;
                int half = c >> 8, i = c & 255, row = i >> 2, k8 = (i & 3)*8;
                ra[j] = *(const short8v*)&(half ? Alo : Ahi)[(size_t)(m0+row)*1024 + k0+32 + k8];
                rb[j] = *(const short8v*)&(half ? Blo : Bhi)[(size_t)(n0+row)*1024 + k0+32 + k8];
            }
        }
        short8v ah0 = *(const short8v*)&Ah[wm +  0 + l15][lk];
        short8v ah1 = *(const short8v*)&Ah[wm + 16 + l15][lk];
        short8v al0 = *(const short8v*)&Al[wm +  0 + l15][lk];
        short8v al1 = *(const short8v*)&Al[wm + 16 + l15][lk];
        short8v bh0 = *(const short8v*)&Bh[wn +  0 + l15][lk];
        short8v bh1 = *(const short8v*)&Bh[wn + 16 + l15][lk];
        short8v bl0 = *(const short8v*)&Bl[wn +  0 + l15][lk];
        short8v bl1 = *(const short8v*)&Bl[wn + 16 + l15][lk];
        MFMA3(acc[0][0], ah0, al0, bh0, bl0);
        MFMA3(acc[0][1], ah0, al0, bh1, bl1);
        MFMA3(acc[1][0], ah1, al1, bh0, bl0);
        MFMA3(acc[1][1], ah1, al1, bh1, bl1);
    }
    int col0 = n0 + wn + l15;
    int rg = lane >> 4;
#pragma unroll
    for (int mf = 0; mf < 2; ++mf)
#pragma unroll
        for (int r = 0; r < 4; ++r){
            int row = m0 + wm + mf*16 + rg*4 + r;
            C[(size_t)row*1536 + col0]      = acc[mf][0][r];
            C[(size_t)row*1536 + col0 + 16] = acc[mf][1][r];
        }
}

// ---------------- fused per-step kernel ----------------
// FUSE=true: A = hn(t) computed inline (GRU) slice-by-slice; also writes Hf/preds (nt==0).
// FUSE=false: A from global splits (used once for gh_0 = h0@Whh^T).
// Block tile 64 rows x 128 cols; 4 waves 2x2; grid (4, n_logits + 12).
template<bool FUSE>
__global__ __launch_bounds__(256) void step_mm(
    const u16* __restrict__ Ahg, const u16* __restrict__ Alg,
    const float* __restrict__ gh, const float* __restrict__ Eproj,
    const float* __restrict__ gictx, const float* __restrict__ bhh,
    const float* __restrict__ hprev, float* __restrict__ hnext,
    const u16* __restrict__ WoHi, const u16* __restrict__ WoLo,
    const u16* __restrict__ WhhHi, const u16* __restrict__ WhhLo,
    const float* __restrict__ bo,
    float* __restrict__ logits, unsigned long long* __restrict__ Pcur,
    const unsigned long long* __restrict__ Pprev,
    float* __restrict__ gh_out, float* __restrict__ preds,
    int n_logits, int t)
{
    __shared__ u16 Ah[64][44], Al[64][44], Bh[128][44], Bl[128][44];
    __shared__ int widx[64];
    int m0 = blockIdx.x * 64;
    int nt = blockIdx.y;
    bool isL = nt < n_logits;
    int nbase = (isL ? nt : nt - n_logits) * 128;
    const u16* Bhg = isL ? WoHi : WhhHi;
    const u16* Blg = isL ? WoLo : WhhLo;
    int tid = threadIdx.x, lane = tid & 63, wid = tid >> 6;
    int wy = wid & 1, wx = wid >> 1;
    int l15 = lane & 15, rg = lane >> 4, lk = rg * 8;
    int ar = tid >> 2, ak8 = (tid & 3) * 8;

    if (FUSE){
        if (tid < 64){
            int b = m0 + tid;
            int w = 1;
            if (t > 0){
                w = 4095 - (int)(Pprev[b] & 0xFFFFFFFFull);
                if (w < 0) w = 0; if (w > 4095) w = 4095;
                if (nt == 0) preds[b*NSTEP + (t-1)] = (float)w;
            }
            widx[tid] = w;
        }
        __syncthreads();
    }

    const u16* agH = Ahg + (size_t)(m0 + ar)*512 + ak8;
    const u16* agL = Alg + (size_t)(m0 + ar)*512 + ak8;
    const u16* bgH0 = Bhg + (size_t)(nbase + ar)*512 + ak8;
    const u16* bgL0 = Blg + (size_t)(nbase + ar)*512 + ak8;
    const u16* bgH1 = bgH0 + (size_t)64*512;
    const u16* bgL1 = bgL0 + (size_t)64*512;

    // GRU-inline state
    int wrow = FUSE ? widx[ar] : 0;
    const int grow = m0 + ar;
    const float* grp = gh + (size_t)grow * 1536;
    const float* epp = Eproj + (size_t)wrow * 1536;
    const float* gcp = gictx + (size_t)grow * 1536;

    ushort4v hnH0, hnH1, hnL0, hnL1;
    short8v ra_h, ra_l;

#define GRU_SLICE(K0) do{                                                     \
    int j = (K0) + ak8;                                                       \
    float G[8], E[8], Cc[8], Bb[8], G2[8], E2[8], C2[8], B2[8];               \
    float G1[8], E1[8], C1[8], B1[8], HP[8], R[8];                            \
    *(float4*)&G[0]  = *(const float4*)&grp[j];                               \
    *(float4*)&G[4]  = *(const float4*)&grp[j+4];                             \
    *(float4*)&G1[0] = *(const float4*)&grp[512+j];                           \
    *(float4*)&G1[4] = *(const float4*)&grp[512+j+4];                         \
    *(float4*)&G2[0] = *(const float4*)&grp[1024+j];                          \
    *(float4*)&G2[4] = *(const float4*)&grp[1024+j+4];                        \
    *(float4*)&E[0]  = *(const float4*)&epp[j];                               \
    *(float4*)&E[4]  = *(const float4*)&epp[j+4];                             \
    *(float4*)&E1[0] = *(const float4*)&epp[512+j];                           \
    *(float4*)&E1[4] = *(const float4*)&epp[512+j+4];                         \
    *(float4*)&E2[0] = *(const float4*)&epp[1024+j];                          \
    *(float4*)&E2[4] = *(const float4*)&epp[1024+j+4];                        \
    *(float4*)&Cc[0] = *(const float4*)&gcp[j];                               \
    *(float4*)&Cc[4] = *(const float4*)&gcp[j+4];                             \
    *(float4*)&C1[0] = *(const float4*)&gcp[512+j];                           \
    *(float4*)&C1[4] = *(const float4*)&gcp[512+j+4];                         \
    *(float4*)&C2[0] = *(const float4*)&gcp[1024+j];                          \
    *(float4*)&C2[4] = *(const float4*)&gcp[1024+j+4];                        \
    *(float4*)&Bb[0] = *(const float4*)&bhh[j];                               \
    *(float4*)&Bb[4] = *(const float4*)&bhh[j+4];                             \
    *(float4*)&B1[0] = *(const float4*)&bhh[512+j];                           \
    *(float4*)&B1[4] = *(const float4*)&bhh[512+j+4];                         \
    *(float4*)&B2[0] = *(const float4*)&bhh[1024+j];                          \
    *(float4*)&B2[4] = *(const float4*)&bhh[1024+j+4];                        \
    *(float4*)&HP[0] = *(const float4*)&hprev[(size_t)grow*512 + j];          \
    *(float4*)&HP[4] = *(const float4*)&hprev[(size_t)grow*512 + j+4];        \
    _Pragma("unroll")                                                         \
    for (int i = 0; i < 8; ++i){                                              \
        float gir = E[i] + Cc[i] + G[i] + Bb[i];                              \
        float giz = E1[i] + C1[i] + G1[i] + B1[i];                            \
        float gin = E2[i] + C2[i];                                            \
        float rr = 1.f / (1.f + expf(-gir));                                  \
        float zz = 1.f / (1.f + expf(-giz));                                  \
        float nn = tanhf(gin + rr * (G2[i] + B2[i]));                         \
        R[i] = (1.f - zz)*nn + zz*HP[i];                                      \
    }                                                                         \
    if (nt == 0){                                                             \
        *(float4*)&hnext[(size_t)grow*512 + j]   = *(float4*)&R[0];           \
        *(float4*)&hnext[(size_t)grow*512 + j+4] = *(float4*)&R[4];           \
    }                                                                         \
    split_f4(*(float4*)&R[0], hnH0, hnL0);                                    \
    split_f4(*(float4*)&R[4], hnH1, hnL1);                                    \
}while(0)

    if (FUSE) GRU_SLICE(0);
    else { ra_h = *(const short8v*)agH; ra_l = *(const short8v*)agL; }

    short8v rb_h0 = *(const short8v*)bgH0;
    short8v rb_l0 = *(const short8v*)bgL0;
    short8v rb_h1 = *(const short8v*)bgH1;
    short8v rb_l1 = *(const short8v*)bgL1;
    f32x4 acc[2][4] = {};

    for (int k0 = 0; k0 < 512; k0 += 32){
        __syncthreads();
        if (FUSE){
            *(ushort4v*)&Ah[ar][ak8]   = hnH0;
            *(ushort4v*)&Ah[ar][ak8+4] = hnH1;
            *(ushort4v*)&Al[ar][ak8]   = hnL0;
            *(ushort4v*)&Al[ar][ak8+4] = hnL1;
        } else {
            *(short8v*)&Ah[ar][ak8] = ra_h;
            *(short8v*)&Al[ar][ak8] = ra_l;
        }
        *(short8v*)&Bh[ar][ak8] = rb_h0;
        *(short8v*)&Bl[ar][ak8] = rb_l0;
        *(short8v*)&Bh[64 + ar][ak8] = rb_h1;
        *(short8v*)&Bl[64 + ar][ak8] = rb_l1;
        __syncthreads();
        if (k0 + 32 < 512){
            if (FUSE) GRU_SLICE(k0 + 32);
            else {
                ra_h = *(const short8v*)(agH + k0 + 32);
                ra_l = *(const short8v*)(agL + k0 + 32);
            }
            rb_h0 = *(const short8v*)(bgH0 + k0 + 32);
            rb_l0 = *(const short8v*)(bgL0 + k0 + 32);
            rb_h1 = *(const short8v*)(bgH1 + k0 + 32);
            rb_l1 = *(const short8v*)(bgL1 + k0 + 32);
        }
        short8v af_h[2], af_l[2];
#pragma unroll
        for (int mf = 0; mf < 2; ++mf){
            af_h[mf] = *(const short8v*)&Ah[wy*32 + mf*16 + l15][lk];
            af_l[mf] = *(const short8v*)&Al[wy*32 + mf*16 + l15][lk];
        }
#pragma unroll
        for (int nf = 0; nf < 4; ++nf){
            short8v bfh = *(const short8v*)&Bh[wx*64 + nf*16 + l15][lk];
            short8v bfl = *(const short8v*)&Bl[wx*64 + nf*16 + l15][lk];
            MFMA3(acc[0][nf], af_h[0], af_l[0], bfh, bfl);
            MFMA3(acc[1][nf], af_h[1], af_l[1], bfh, bfl);
        }
    }
    if (isL){
        float bov[4];
#pragma unroll
        for (int nf = 0; nf < 4; ++nf) bov[nf] = bo[nbase + wx*64 + nf*16 + l15];
#pragma unroll
        for (int mf = 0; mf < 2; ++mf){
#pragma unroll
            for (int r = 0; r < 4; ++r){
                int row = m0 + wy*32 + mf*16 + rg*4 + r;
                float* crow = logits + (size_t)row * (NSTEP * (size_t)V_);
                unsigned long long best = 0ULL;
#pragma unroll
                for (int nf = 0; nf < 4; ++nf){
                    int col = nbase + wx*64 + nf*16 + l15;
                    float v = acc[mf][nf][r] + bov[nf];
                    crow[col] = v;
                    unsigned long long key = ((unsigned long long)fkey(v) << 32) | (unsigned)(4095 - col);
                    if (key > best) best = key;
                }
#pragma unroll
                for (int off = 1; off < 16; off <<= 1){
                    unsigned long long o = __shfl_xor(best, off);
                    if (o > best) best = o;
                }
                if (l15 == 0) atomicMax(&Pcur[row], best);
            }
        }
    } else {
#pragma unroll
        for (int mf = 0; mf < 2; ++mf)
#pragma unroll
            for (int nf = 0; nf < 4; ++nf)
#pragma unroll
                for (int r = 0; r < 4; ++r){
                    int row = m0 + wy*32 + mf*16 + rg*4 + r;
                    int col = nbase + wx*64 + nf*16 + l15;
                    gh_out[(size_t)row*1536 + col] = acc[mf][nf][r];
                }
    }
}

__global__ __launch_bounds__(256) void final_pred(const unsigned long long* __restrict__ P,
                                                  float* __restrict__ preds){
    int b = threadIdx.x;
    int w = 4095 - (int)(P[b] & 0xFFFFFFFFull);
    if (w < 0) w = 0; if (w > 4095) w = 4095;
    preds[b*NSTEP + (NSTEP-1)] = (float)w;
}

extern "C" void kernel_launch(void* const* d_in, const int* in_sizes, int n_in,
                              void* d_out, int out_size, void* d_ws, size_t ws_size,
                              hipStream_t stream){
    const float* elhs = (const float*)d_in[0];
    const float* enc  = (const float*)d_in[1];
    const float* emb  = (const float*)d_in[3];
    const float* W1   = (const float*)d_in[4];
    const float* W2   = (const float*)d_in[6];
    const float* W3   = (const float*)d_in[8];
    const float* W4   = (const float*)d_in[10];
    const float* Ww   = (const float*)d_in[12];
    const float* Wih  = (const float*)d_in[13];
    const float* bih  = (const float*)d_in[14];
    const float* Whh  = (const float*)d_in[15];
    const float* bhh  = (const float*)d_in[16];
    const float* Wo   = (const float*)d_in[17];
    const float* bo   = (const float*)d_in[18];

    float* out = (float*)d_out;
    float* preds = out + (size_t)B_ * NSTEP * V_;

    float* ws = (float*)d_ws;
    float* Eproj  = ws;  ws += (size_t)V_ * 1536;
    float* gictx  = ws;  ws += (size_t)B_ * 1536;
    float* ctx    = ws;  ws += B_ * H_;
    float* scores = ws;  ws += B_ * S_;
    float* t1     = ws;  ws += 512;
    float* t2     = ws;  ws += 512;
    float* weff   = ws;  ws += 512;
    float* Hf     = ws;  ws += 2 * B_ * H_;
    float* ghA    = ws;  ws += B_ * 1536;
    float* ghB    = ws;  ws += B_ * 1536;
    u16* WoT_hi = (u16*)ws;  ws += (size_t)V_ * 512 / 2;
    u16* WoT_lo = (u16*)ws;  ws += (size_t)V_ * 512 / 2;
    u16* WhhHi  = (u16*)ws;  ws += 1536 * 512 / 2;
    u16* WhhLo  = (u16*)ws;  ws += 1536 * 512 / 2;
    u16* Sh     = (u16*)ws;  ws += B_ * H_ / 2;
    u16* Sl     = (u16*)ws;  ws += B_ * H_ / 2;
    unsigned long long* P = (unsigned long long*)ws;   // 27*256 u64

    // big one-time splits parked in d_out head (consumed by eproj before logits writes)
    u16* EmbHi  = (u16*)d_out;
    u16* EmbLo  = EmbHi + (size_t)V_*1024;
    u16* WihLHi = EmbLo + (size_t)V_*1024;
    u16* WihLLo = WihLHi + (size_t)1536*1024;

    prep_all<<<7054, 256, 0, stream>>>(Whh, Wo, emb, Wih, elhs,
                                       WhhHi, WhhLo, WoT_hi, WoT_lo,
                                       EmbHi, EmbLo, WihLHi, WihLLo,
                                       Sh, Sl, (unsigned*)P, NSTEP*256*2);

    matvec512<<<512, 64, 0, stream>>>(W4, Ww, t1);
    matvec512<<<512, 64, 0, stream>>>(W3, t1, t2);
    matvec512<<<512, 64, 0, stream>>>(W2, t2, t1);
    matvec512<<<512, 64, 0, stream>>>(W1, t1, weff);
    score_kernel<<<(B_*S_)/4, 256, 0, stream>>>(enc, weff, scores);
    softmax_ctx<<<B_, 512, 0, stream>>>(enc, scores, ctx);
    { dim3 g(B_/32, 1536/64);
      gemm_abt<32><<<g, 256, 0, stream>>>(ctx, 512, Wih + 1024, 1536, bih, gictx, 1536, 512); }
    { dim3 g(1536/64, V_/64);
      eproj_u16<<<g, 256, 0, stream>>>(EmbHi, EmbLo, WihLHi, WihLLo, Eproj); }

    // gh_0 = h0 @ Whh^T  (A from prep's h0 splits)
    { dim3 g(4, 12);
      step_mm<false><<<g, 256, 0, stream>>>(Sh, Sl,
          nullptr, nullptr, nullptr, nullptr, nullptr, nullptr,
          WoT_hi, WoT_lo, WhhHi, WhhLo, bo,
          out, P, P, ghA, preds, 0, 0); }

    for (int t = 0; t < NSTEP; ++t){
        const float* gh_in  = (t & 1) ? ghB : ghA;
        float*       gh_nx  = (t & 1) ? ghA : ghB;
        const float* hr = (t == 0) ? elhs : (Hf + (size_t)((t-1) & 1) * (B_*H_));
        float*       hw = Hf + (size_t)(t & 1) * (B_*H_);
        dim3 g(4, 32 + 12);
        step_mm<true><<<g, 256, 0, stream>>>(Sh, Sl,
            gh_in, Eproj, gictx, bhh, hr, hw,
            WoT_hi, WoT_lo, WhhHi, WhhLo, bo,
            out + (size_t)t * V_, P + (size_t)t*256,
            (t > 0) ? (P + (size_t)(t-1)*256) : P,
            gh_nx, preds, 32, t);
    }
    final_pred<<<1, 256, 0, stream>>>(P + (size_t)(NSTEP-1)*256, preds);
}

// Round 8
// 938.187 us; speedup vs baseline: 1.7618x; 1.7618x over previous
//
#include <hip/hip_runtime.h>

#define B_ 256
#define S_ 80
#define H_ 512
#define V_ 4096
#define NSTEP 27

typedef unsigned short u16;
typedef __attribute__((ext_vector_type(8))) short short8v;
typedef __attribute__((ext_vector_type(4))) float f32x4;
typedef __attribute__((ext_vector_type(4))) unsigned short ushort4v;

#define MFMA_(a,b,c) __builtin_amdgcn_mfma_f32_16x16x32_bf16(a,b,c,0,0,0)
#define MFMA3(acc, ah, al, bh, bl) do{ acc = MFMA_(ah,bh,acc); acc = MFMA_(ah,bl,acc); acc = MFMA_(al,bh,acc);}while(0)

__device__ __forceinline__ unsigned fkey(float v){
    unsigned u = __float_as_uint(v);
    return (u & 0x80000000u) ? ~u : (u | 0x80000000u);
}
__device__ __forceinline__ u16 bf16_rne(float f){
    unsigned u = __float_as_uint(f);
    return (u16)((u + 0x7FFFu + ((u >> 16) & 1u)) >> 16);
}
__device__ __forceinline__ void split_f4(float4 v, ushort4v& hi, ushort4v& lo){
    float arr[4] = {v.x, v.y, v.z, v.w};
    ushort4v h, l;
#pragma unroll
    for (int i = 0; i < 4; ++i){
        u16 hb = bf16_rne(arr[i]);
        h[i] = hb;
        l[i] = bf16_rne(arr[i] - __uint_as_float(((unsigned)hb) << 16));
    }
    hi = h; lo = l;
}

// ---------------- front ----------------
__global__ __launch_bounds__(64) void matvec512(const float* __restrict__ W,
                                                const float* __restrict__ v,
                                                float* __restrict__ out){
    int row = blockIdx.x, lane = threadIdx.x;
    const float* wr = W + row * 512;
    float s = 0.f;
#pragma unroll
    for (int i = 0; i < 8; ++i) s += wr[lane + 64*i] * v[lane + 64*i];
#pragma unroll
    for (int off = 32; off; off >>= 1) s += __shfl_xor(s, off);
    if (lane == 0) out[row] = s;
}

__global__ __launch_bounds__(256) void score_kernel(const float* __restrict__ enc,
                                                    const float* __restrict__ weff,
                                                    float* __restrict__ scores){
    int wv = threadIdx.x >> 6, lane = threadIdx.x & 63;
    int p = blockIdx.x * 4 + wv;
    const float* e = enc + (size_t)p * 512;
    float s = 0.f;
#pragma unroll
    for (int i = 0; i < 8; ++i) s += e[lane + 64*i] * weff[lane + 64*i];
#pragma unroll
    for (int off = 32; off; off >>= 1) s += __shfl_xor(s, off);
    if (lane == 0) scores[p] = s;
}

__global__ __launch_bounds__(512) void softmax_ctx(const float* __restrict__ enc,
                                                   const float* __restrict__ scores,
                                                   float* __restrict__ ctx){
    __shared__ float att[S_];
    int b = blockIdx.x, tid = threadIdx.x;
    if (tid < S_) att[tid] = scores[b*S_ + tid];
    __syncthreads();
    if (tid == 0){
        float mx = att[0];
        for (int s = 1; s < S_; ++s) mx = fmaxf(mx, att[s]);
        float sum = 0.f;
        for (int s = 0; s < S_; ++s){ float e = expf(att[s] - mx); att[s] = e; sum += e; }
        float inv = 1.f / sum;
        for (int s = 0; s < S_; ++s) att[s] *= inv;
    }
    __syncthreads();
    float a = 0.f;
    const float* eb = enc + (size_t)b * (S_*H_);
    for (int s = 0; s < S_; ++s) a += att[s] * eb[s*H_ + tid];
    ctx[b*H_ + tid] = a;
}

template<int TM>
__global__ __launch_bounds__(256) void gemm_abt(const float* __restrict__ A, int lda,
                                                const float* __restrict__ Bm, int ldb,
                                                const float* __restrict__ bias,
                                                float* __restrict__ C, int ldc, int K){
    constexpr int RPT = TM / 16;
    __shared__ float As[16][TM + 4];
    __shared__ float Bs[16][64 + 4];
    int m0 = blockIdx.x * TM, n0 = blockIdx.y * 64;
    int tid = threadIdx.x;
    int lk = tid & 15, lr = tid >> 4;
    int tx = tid & 15, ty = tid >> 4;
    float c[RPT][4] = {};
    for (int k0 = 0; k0 < K; k0 += 16){
#pragma unroll
        for (int i = 0; i < RPT; ++i)
            As[lk][lr*RPT + i] = A[(size_t)(m0 + lr*RPT + i)*lda + k0 + lk];
#pragma unroll
        for (int i = 0; i < 4; ++i)
            Bs[lk][lr*4 + i] = Bm[(size_t)(n0 + lr*4 + i)*ldb + k0 + lk];
        __syncthreads();
#pragma unroll
        for (int k = 0; k < 16; ++k){
            float b4[4];
            *(float4*)b4 = *(const float4*)&Bs[k][tx*4];
#pragma unroll
            for (int i = 0; i < RPT; ++i){
                float a = As[k][ty*RPT + i];
#pragma unroll
                for (int j = 0; j < 4; ++j) c[i][j] += a * b4[j];
            }
        }
        __syncthreads();
    }
#pragma unroll
    for (int j = 0; j < 4; ++j){
        float bb = bias ? bias[n0 + tx*4 + j] : 0.f;
#pragma unroll
        for (int i = 0; i < RPT; ++i)
            C[(size_t)(m0 + ty*RPT + i)*ldc + n0 + tx*4 + j] = c[i][j] + bb;
    }
}

// ---------------- one-time transforms fused into a single kernel ----------------
__global__ __launch_bounds__(256) void prep_all(
    const float* __restrict__ Whh, const float* __restrict__ Wo,
    const float* __restrict__ emb, const float* __restrict__ Wih,
    const float* __restrict__ elhs,
    u16* __restrict__ WhhHi, u16* __restrict__ WhhLo,
    u16* __restrict__ WoThi, u16* __restrict__ WoTlo,
    u16* __restrict__ EmbHi, u16* __restrict__ EmbLo,
    u16* __restrict__ WihLHi, u16* __restrict__ WihLLo,
    u16* __restrict__ Sh, u16* __restrict__ Sl,
    unsigned* __restrict__ zp, int nz)
{
    __shared__ float T[64][65];
    int b = blockIdx.x, tid = threadIdx.x;
    if (b < 768){
        int idx = (b*256 + tid)*4;
        float4 v = *(const float4*)&Whh[idx];
        ushort4v h,l; split_f4(v,h,l);
        *(ushort4v*)&WhhHi[idx]=h; *(ushort4v*)&WhhLo[idx]=l;
    } else if (b < 1280){
        int lb = b - 768;
        int k0 = (lb & 7)*64, n0 = (lb >> 3)*64;
#pragma unroll
        for (int i = 0; i < 16; ++i){
            int idx = tid + i*256;
            int kk = idx >> 6, nn = idx & 63;
            T[kk][nn] = Wo[(size_t)(k0+kk)*4096 + n0+nn];
        }
        __syncthreads();
#pragma unroll
        for (int i = 0; i < 16; ++i){
            int idx = tid + i*256;
            int nn = idx >> 6, kk = idx & 63;
            float v = T[kk][nn];
            u16 hi = bf16_rne(v);
            u16 lo = bf16_rne(v - __uint_as_float(((unsigned)hi) << 16));
            size_t o = (size_t)(n0+nn)*512 + k0+kk;
            WoThi[o] = hi; WoTlo[o] = lo;
        }
    } else if (b < 5376){
        int idx = ((b-1280)*256 + tid)*4;
        float4 v = *(const float4*)&emb[idx];
        ushort4v h,l; split_f4(v,h,l);
        *(ushort4v*)&EmbHi[idx]=h; *(ushort4v*)&EmbLo[idx]=l;
    } else if (b < 6912){
        int id = ((b-5376)*256 + tid)*4;
        int r = id >> 10, c = id & 1023;
        float4 v = *(const float4*)&Wih[(size_t)r*1536 + c];
        ushort4v h,l; split_f4(v,h,l);
        *(ushort4v*)&WihLHi[id]=h; *(ushort4v*)&WihLLo[id]=l;
    } else if (b < 7040){
        int idx = ((b-6912)*256 + tid)*4;
        float4 v = *(const float4*)&elhs[idx];
        ushort4v h,l; split_f4(v,h,l);
        *(ushort4v*)&Sh[idx]=h; *(ushort4v*)&Sl[idx]=l;
    } else {
        int i = ((b-7040)*256 + tid)*4;
        if (i < nz){ zp[i]=0u; zp[i+1]=0u; zp[i+2]=0u; zp[i+3]=0u; }
    }
}

// ---------------- Eproj: emb(4096x1024) @ WihL^T(1536x1024) ----------------
__global__ __launch_bounds__(256) void eproj_u16(const u16* __restrict__ Ahi, const u16* __restrict__ Alo,
                                                 const u16* __restrict__ Bhi, const u16* __restrict__ Blo,
                                                 float* __restrict__ C){
    __shared__ u16 Ah[64][44], Al[64][44], Bh[64][44], Bl[64][44];
    int n0 = blockIdx.x * 64, m0 = blockIdx.y * 64;
    int tid = threadIdx.x, lane = tid & 63, wid = tid >> 6;
    int wm = (wid & 1) * 32, wn = (wid >> 1) * 32;
    int l15 = lane & 15, lk = (lane >> 4) * 8;
    f32x4 acc[2][2] = {};
    short8v ra[2], rb[2];
#pragma unroll
    for (int j = 0; j < 2; ++j){
        int c = j*256 + tid;
        int half = c >> 8, i = c & 255, row = i >> 2, k8 = (i & 3)*8;
        ra[j] = *(const short8v*)&(half ? Alo : Ahi)[(size_t)(m0+row)*1024 + k8];
        rb[j] = *(const short8v*)&(half ? Blo : Bhi)[(size_t)(n0+row)*1024 + k8];
    }
    for (int k0 = 0; k0 < 1024; k0 += 32){
        __syncthreads();
#pragma unroll
        for (int j = 0; j < 2; ++j){
            int c = j*256 + tid;
            int half = c >> 8, i = c & 255, row = i >> 2, k8 = (i & 3)*8;
            if (half){ *(short8v*)&Al[row][k8] = ra[j]; *(short8v*)&Bl[row][k8] = rb[j]; }
            else     { *(short8v*)&Ah[row][k8] = ra[j]; *(short8v*)&Bh[row][k8] = rb[j]; }
        }
        __syncthreads();
        if (k0 + 32 < 1024){
#pragma unroll
            for (int j = 0; j < 2; ++j){
                int c = j*256 + tid;
                int half = c >> 8, i = c & 255, row = i >> 2, k8 = (i & 3)*8;
                ra[j] = *(const short8v*)&(half ? Alo : Ahi)[(size_t)(m0+row)*1024 + k0+32 + k8];
                rb[j] = *(const short8v*)&(half ? Blo : Bhi)[(size_t)(n0+row)*1024 + k0+32 + k8];
            }
        }
        short8v ah0 = *(const short8v*)&Ah[wm +  0 + l15][lk];
        short8v ah1 = *(const short8v*)&Ah[wm + 16 + l15][lk];
        short8v al0 = *(const short8v*)&Al[wm +  0 + l15][lk];
        short8v al1 = *(const short8v*)&Al[wm + 16 + l15][lk];
        short8v bh0 = *(const short8v*)&Bh[wn +  0 + l15][lk];
        short8v bh1 = *(const short8v*)&Bh[wn + 16 + l15][lk];
        short8v bl0 = *(const short8v*)&Bl[wn +  0 + l15][lk];
        short8v bl1 = *(const short8v*)&Bl[wn + 16 + l15][lk];
        MFMA3(acc[0][0], ah0, al0, bh0, bl0);
        MFMA3(acc[0][1], ah0, al0, bh1, bl1);
        MFMA3(acc[1][0], ah1, al1, bh0, bl0);
        MFMA3(acc[1][1], ah1, al1, bh1, bl1);
    }
    int col0 = n0 + wn + l15;
    int rg = lane >> 4;
#pragma unroll
    for (int mf = 0; mf < 2; ++mf)
#pragma unroll
        for (int r = 0; r < 4; ++r){
            int row = m0 + wm + mf*16 + rg*4 + r;
            C[(size_t)row*1536 + col0]      = acc[mf][0][r];
            C[(size_t)row*1536 + col0 + 16] = acc[mf][1][r];
        }
}

// ---------------- per-step kernels ----------------

// GRU pointwise (proven round-6 form).
__global__ __launch_bounds__(256) void gru_pointwise(
    const float* __restrict__ gh, const float* __restrict__ Eproj,
    const float* __restrict__ gictx, const float* __restrict__ bhh,
    const float* __restrict__ hprev, float* __restrict__ hnext,
    u16* __restrict__ Sh, u16* __restrict__ Sl,
    const unsigned long long* __restrict__ Pprev,
    float* __restrict__ preds, int t)
{
    int tid = threadIdx.x;
    int row = blockIdx.x * 2 + (tid >> 7);
    int jj = (tid & 127) * 4;
    int w = 1;
    if (t > 0){
        w = 4095 - (int)(Pprev[row] & 0xFFFFFFFFull);
        if (w < 0) w = 0; if (w > 4095) w = 4095;
        if (jj == 0) preds[row*NSTEP + (t-1)] = (float)w;
    }
    const float* gr = gh + (size_t)row * 1536;
    const float* ep = Eproj + (size_t)w * 1536;
    const float* gc = gictx + (size_t)row * 1536;
    float4 g0 = *(const float4*)&gr[jj];
    float4 g1 = *(const float4*)&gr[512 + jj];
    float4 g2 = *(const float4*)&gr[1024 + jj];
    float4 e0 = *(const float4*)&ep[jj];
    float4 e1 = *(const float4*)&ep[512 + jj];
    float4 e2 = *(const float4*)&ep[1024 + jj];
    float4 c0 = *(const float4*)&gc[jj];
    float4 c1 = *(const float4*)&gc[512 + jj];
    float4 c2 = *(const float4*)&gc[1024 + jj];
    float4 b0 = *(const float4*)&bhh[jj];
    float4 b1 = *(const float4*)&bhh[512 + jj];
    float4 b2 = *(const float4*)&bhh[1024 + jj];
    float4 ho = *(const float4*)&hprev[(size_t)row*512 + jj];
    const float* G0 = (const float*)&g0; const float* G1 = (const float*)&g1;
    const float* G2 = (const float*)&g2;
    const float* E0 = (const float*)&e0; const float* E1 = (const float*)&e1;
    const float* E2 = (const float*)&e2;
    const float* C0 = (const float*)&c0; const float* C1 = (const float*)&c1;
    const float* C2 = (const float*)&c2;
    const float* B0 = (const float*)&b0; const float* B1 = (const float*)&b1;
    const float* B2 = (const float*)&b2;
    const float* HO = (const float*)&ho;
    float4 res;
    float* R = (float*)&res;
#pragma unroll
    for (int i = 0; i < 4; ++i){
        float gir = E0[i] + C0[i] + G0[i] + B0[i];
        float giz = E1[i] + C1[i] + G1[i] + B1[i];
        float gin = E2[i] + C2[i];
        float rr = 1.f / (1.f + expf(-gir));
        float zz = 1.f / (1.f + expf(-giz));
        float nn = tanhf(gin + rr * (G2[i] + B2[i]));
        R[i] = (1.f - zz)*nn + zz*HO[i];
    }
    size_t o = (size_t)row*512 + jj;
    *(float4*)&hnext[o] = res;
    ushort4v h4, l4; split_f4(res, h4, l4);
    *(ushort4v*)&Sh[o] = h4;
    *(ushort4v*)&Sl[o] = l4;
}

// Fused logits(t)+argmax / gh(t+1) GEMM. Tile 64x64, 4 waves 2x2 (32x32 each).
// A fragments read DIRECTLY from global (Sh/Sl, L2-hot); B staged in LDS (pad 44).
// grid (4, n_logits + 24); nt < n_logits -> logits 64-col tile; else gh tile.
__global__ __launch_bounds__(256) void step_mm(
    const u16* __restrict__ Ahg, const u16* __restrict__ Alg,
    const u16* __restrict__ WoHi, const u16* __restrict__ WoLo,
    const u16* __restrict__ WhhHi, const u16* __restrict__ WhhLo,
    const float* __restrict__ bo,
    float* __restrict__ logits, unsigned long long* __restrict__ Pcur,
    float* __restrict__ gh_out, int n_logits)
{
    __shared__ u16 Bh[64][44], Bl[64][44];
    int m0 = blockIdx.x * 64;
    int nt = blockIdx.y;
    bool isL = nt < n_logits;
    int nbase = (isL ? nt : nt - n_logits) * 64;
    const u16* Bhg = isL ? WoHi : WhhHi;
    const u16* Blg = isL ? WoLo : WhhLo;
    int tid = threadIdx.x, lane = tid & 63, wid = tid >> 6;
    int wy = wid & 1, wx = wid >> 1;
    int l15 = lane & 15, rg = lane >> 4, lk = rg * 8;
    int ar = tid >> 2, ak8 = (tid & 3) * 8;

    const u16* bgH = Bhg + (size_t)(nbase + ar)*512 + ak8;
    const u16* bgL = Blg + (size_t)(nbase + ar)*512 + ak8;
    // A fragment pointers: row = m0 + wy*32 + mf*16 + l15, col = k + lk
    const u16* agH0 = Ahg + (size_t)(m0 + wy*32 +  0 + l15)*512 + lk;
    const u16* agH1 = Ahg + (size_t)(m0 + wy*32 + 16 + l15)*512 + lk;
    const u16* agL0 = Alg + (size_t)(m0 + wy*32 +  0 + l15)*512 + lk;
    const u16* agL1 = Alg + (size_t)(m0 + wy*32 + 16 + l15)*512 + lk;

    f32x4 acc[2][2] = {};
    short8v rb_h = *(const short8v*)bgH;
    short8v rb_l = *(const short8v*)bgL;
    short8v ah0 = *(const short8v*)agH0;
    short8v ah1 = *(const short8v*)agH1;
    short8v al0 = *(const short8v*)agL0;
    short8v al1 = *(const short8v*)agL1;

    for (int k0 = 0; k0 < 512; k0 += 32){
        __syncthreads();
        *(short8v*)&Bh[ar][ak8] = rb_h;
        *(short8v*)&Bl[ar][ak8] = rb_l;
        __syncthreads();
        short8v nah0, nah1, nal0, nal1;
        if (k0 + 32 < 512){
            rb_h = *(const short8v*)(bgH + k0 + 32);
            rb_l = *(const short8v*)(bgL + k0 + 32);
            nah0 = *(const short8v*)(agH0 + k0 + 32);
            nah1 = *(const short8v*)(agH1 + k0 + 32);
            nal0 = *(const short8v*)(agL0 + k0 + 32);
            nal1 = *(const short8v*)(agL1 + k0 + 32);
        }
        short8v bh0 = *(const short8v*)&Bh[wx*32 +  0 + l15][lk];
        short8v bh1 = *(const short8v*)&Bh[wx*32 + 16 + l15][lk];
        short8v bl0 = *(const short8v*)&Bl[wx*32 +  0 + l15][lk];
        short8v bl1 = *(const short8v*)&Bl[wx*32 + 16 + l15][lk];
        MFMA3(acc[0][0], ah0, al0, bh0, bl0);
        MFMA3(acc[0][1], ah0, al0, bh1, bl1);
        MFMA3(acc[1][0], ah1, al1, bh0, bl0);
        MFMA3(acc[1][1], ah1, al1, bh1, bl1);
        if (k0 + 32 < 512){
            ah0 = nah0; ah1 = nah1; al0 = nal0; al1 = nal1;
        }
    }
    if (isL){
        int col0 = nbase + wx*32 + l15;
        float bo0 = bo[col0], bo1 = bo[col0 + 16];
#pragma unroll
        for (int mf = 0; mf < 2; ++mf){
#pragma unroll
            for (int r = 0; r < 4; ++r){
                int row = m0 + wy*32 + mf*16 + rg*4 + r;
                float v0 = acc[mf][0][r] + bo0;
                float v1 = acc[mf][1][r] + bo1;
                float* crow = logits + (size_t)row * (NSTEP * (size_t)V_);
                crow[col0]      = v0;
                crow[col0 + 16] = v1;
                unsigned long long k0_ = ((unsigned long long)fkey(v0) << 32) | (unsigned)(4095 - col0);
                unsigned long long k1_ = ((unsigned long long)fkey(v1) << 32) | (unsigned)(4095 - (col0+16));
                unsigned long long best = k0_ > k1_ ? k0_ : k1_;
#pragma unroll
                for (int off = 1; off < 16; off <<= 1){
                    unsigned long long o = __shfl_xor(best, off);
                    if (o > best) best = o;
                }
                if (l15 == 0) atomicMax(&Pcur[row], best);
            }
        }
    } else {
        int col0 = nbase + wx*32 + l15;
#pragma unroll
        for (int mf = 0; mf < 2; ++mf)
#pragma unroll
            for (int r = 0; r < 4; ++r){
                int row = m0 + wy*32 + mf*16 + rg*4 + r;
                gh_out[(size_t)row*1536 + col0]      = acc[mf][0][r];
                gh_out[(size_t)row*1536 + col0 + 16] = acc[mf][1][r];
            }
    }
}

__global__ __launch_bounds__(256) void final_pred(const unsigned long long* __restrict__ P,
                                                  float* __restrict__ preds){
    int b = threadIdx.x;
    int w = 4095 - (int)(P[b] & 0xFFFFFFFFull);
    if (w < 0) w = 0; if (w > 4095) w = 4095;
    preds[b*NSTEP + (NSTEP-1)] = (float)w;
}

extern "C" void kernel_launch(void* const* d_in, const int* in_sizes, int n_in,
                              void* d_out, int out_size, void* d_ws, size_t ws_size,
                              hipStream_t stream){
    const float* elhs = (const float*)d_in[0];
    const float* enc  = (const float*)d_in[1];
    const float* emb  = (const float*)d_in[3];
    const float* W1   = (const float*)d_in[4];
    const float* W2   = (const float*)d_in[6];
    const float* W3   = (const float*)d_in[8];
    const float* W4   = (const float*)d_in[10];
    const float* Ww   = (const float*)d_in[12];
    const float* Wih  = (const float*)d_in[13];
    const float* bih  = (const float*)d_in[14];
    const float* Whh  = (const float*)d_in[15];
    const float* bhh  = (const float*)d_in[16];
    const float* Wo   = (const float*)d_in[17];
    const float* bo   = (const float*)d_in[18];

    float* out = (float*)d_out;
    float* preds = out + (size_t)B_ * NSTEP * V_;

    float* ws = (float*)d_ws;
    float* Eproj  = ws;  ws += (size_t)V_ * 1536;
    float* gictx  = ws;  ws += (size_t)B_ * 1536;
    float* ctx    = ws;  ws += B_ * H_;
    float* scores = ws;  ws += B_ * S_;
    float* t1     = ws;  ws += 512;
    float* t2     = ws;  ws += 512;
    float* weff   = ws;  ws += 512;
    float* Hf     = ws;  ws += 2 * B_ * H_;
    float* ghbuf  = ws;  ws += B_ * 1536;
    u16* WoT_hi = (u16*)ws;  ws += (size_t)V_ * 512 / 2;
    u16* WoT_lo = (u16*)ws;  ws += (size_t)V_ * 512 / 2;
    u16* WhhHi  = (u16*)ws;  ws += 1536 * 512 / 2;
    u16* WhhLo  = (u16*)ws;  ws += 1536 * 512 / 2;
    u16* Sh     = (u16*)ws;  ws += B_ * H_ / 2;
    u16* Sl     = (u16*)ws;  ws += B_ * H_ / 2;
    unsigned long long* P = (unsigned long long*)ws;   // 27*256 u64

    // big one-time splits parked in d_out head (consumed by eproj before logits writes)
    u16* EmbHi  = (u16*)d_out;
    u16* EmbLo  = EmbHi + (size_t)V_*1024;
    u16* WihLHi = EmbLo + (size_t)V_*1024;
    u16* WihLLo = WihLHi + (size_t)1536*1024;

    prep_all<<<7054, 256, 0, stream>>>(Whh, Wo, emb, Wih, elhs,
                                       WhhHi, WhhLo, WoT_hi, WoT_lo,
                                       EmbHi, EmbLo, WihLHi, WihLLo,
                                       Sh, Sl, (unsigned*)P, NSTEP*256*2);

    matvec512<<<512, 64, 0, stream>>>(W4, Ww, t1);
    matvec512<<<512, 64, 0, stream>>>(W3, t1, t2);
    matvec512<<<512, 64, 0, stream>>>(W2, t2, t1);
    matvec512<<<512, 64, 0, stream>>>(W1, t1, weff);
    score_kernel<<<(B_*S_)/4, 256, 0, stream>>>(enc, weff, scores);
    softmax_ctx<<<B_, 512, 0, stream>>>(enc, scores, ctx);
    { dim3 g(B_/32, 1536/64);
      gemm_abt<32><<<g, 256, 0, stream>>>(ctx, 512, Wih + 1024, 1536, bih, gictx, 1536, 512); }
    { dim3 g(1536/64, V_/64);
      eproj_u16<<<g, 256, 0, stream>>>(EmbHi, EmbLo, WihLHi, WihLLo, Eproj); }

    // gh_0 = h0 @ Whh^T
    { dim3 g(4, 24);
      step_mm<<<g, 256, 0, stream>>>(Sh, Sl, WoT_hi, WoT_lo, WhhHi, WhhLo, bo,
                                     out, P, ghbuf, 0); }

    for (int t = 0; t < NSTEP; ++t){
        const float* hr = (t == 0) ? elhs : (Hf + (size_t)((t-1) & 1) * (B_*H_));
        float*       hw = Hf + (size_t)(t & 1) * (B_*H_);
        const unsigned long long* Pprev = P + (size_t)(t > 0 ? t-1 : 0) * 256;
        gru_pointwise<<<128, 256, 0, stream>>>(ghbuf, Eproj, gictx, bhh, hr, hw,
                                               Sh, Sl, Pprev, preds, t);
        dim3 g(4, 64 + 24);
        step_mm<<<g, 256, 0, stream>>>(Sh, Sl, WoT_hi, WoT_lo, WhhHi, WhhLo, bo,
                                       out + (size_t)t * V_, P + (size_t)t*256, ghbuf, 64);
    }
    final_pred<<<1, 256, 0, stream>>>(P + (size_t)(NSTEP-1)*256, preds);
}

// Round 9
// 763.242 us; speedup vs baseline: 2.1656x; 1.2292x over previous
//
#include <hip/hip_runtime.h>

#define B_ 256
#define S_ 80
#define H_ 512
#define V_ 4096
#define NSTEP 27

typedef unsigned short u16;
typedef __attribute__((ext_vector_type(8))) short short8v;
typedef __attribute__((ext_vector_type(4))) float f32x4;
typedef __attribute__((ext_vector_type(4))) unsigned short ushort4v;

#define MFMA_(a,b,c) __builtin_amdgcn_mfma_f32_16x16x32_bf16(a,b,c,0,0,0)
#define MFMA3(acc, ah, al, bh, bl) do{ acc = MFMA_(ah,bh,acc); acc = MFMA_(ah,bl,acc); acc = MFMA_(al,bh,acc);}while(0)

__device__ __forceinline__ unsigned fkey(float v){
    unsigned u = __float_as_uint(v);
    return (u & 0x80000000u) ? ~u : (u | 0x80000000u);
}
__device__ __forceinline__ u16 bf16_rne(float f){
    unsigned u = __float_as_uint(f);
    return (u16)((u + 0x7FFFu + ((u >> 16) & 1u)) >> 16);
}
__device__ __forceinline__ void split_f4(float4 v, ushort4v& hi, ushort4v& lo){
    float arr[4] = {v.x, v.y, v.z, v.w};
    ushort4v h, l;
#pragma unroll
    for (int i = 0; i < 4; ++i){
        u16 hb = bf16_rne(arr[i]);
        h[i] = hb;
        l[i] = bf16_rne(arr[i] - __uint_as_float(((unsigned)hb) << 16));
    }
    hi = h; lo = l;
}

// ---------------- front ----------------
__global__ __launch_bounds__(64) void matvec512(const float* __restrict__ W,
                                                const float* __restrict__ v,
                                                float* __restrict__ out){
    int row = blockIdx.x, lane = threadIdx.x;
    const float* wr = W + row * 512;
    float s = 0.f;
#pragma unroll
    for (int i = 0; i < 8; ++i) s += wr[lane + 64*i] * v[lane + 64*i];
#pragma unroll
    for (int off = 32; off; off >>= 1) s += __shfl_xor(s, off);
    if (lane == 0) out[row] = s;
}

__global__ __launch_bounds__(256) void score_kernel(const float* __restrict__ enc,
                                                    const float* __restrict__ weff,
                                                    float* __restrict__ scores){
    int wv = threadIdx.x >> 6, lane = threadIdx.x & 63;
    int p = blockIdx.x * 4 + wv;
    const float* e = enc + (size_t)p * 512;
    float s = 0.f;
#pragma unroll
    for (int i = 0; i < 8; ++i) s += e[lane + 64*i] * weff[lane + 64*i];
#pragma unroll
    for (int off = 32; off; off >>= 1) s += __shfl_xor(s, off);
    if (lane == 0) scores[p] = s;
}

__global__ __launch_bounds__(512) void softmax_ctx(const float* __restrict__ enc,
                                                   const float* __restrict__ scores,
                                                   float* __restrict__ ctx){
    __shared__ float att[S_];
    int b = blockIdx.x, tid = threadIdx.x;
    if (tid < S_) att[tid] = scores[b*S_ + tid];
    __syncthreads();
    if (tid == 0){
        float mx = att[0];
        for (int s = 1; s < S_; ++s) mx = fmaxf(mx, att[s]);
        float sum = 0.f;
        for (int s = 0; s < S_; ++s){ float e = expf(att[s] - mx); att[s] = e; sum += e; }
        float inv = 1.f / sum;
        for (int s = 0; s < S_; ++s) att[s] *= inv;
    }
    __syncthreads();
    float a = 0.f;
    const float* eb = enc + (size_t)b * (S_*H_);
    for (int s = 0; s < S_; ++s) a += att[s] * eb[s*H_ + tid];
    ctx[b*H_ + tid] = a;
}

template<int TM>
__global__ __launch_bounds__(256) void gemm_abt(const float* __restrict__ A, int lda,
                                                const float* __restrict__ Bm, int ldb,
                                                const float* __restrict__ bias,
                                                float* __restrict__ C, int ldc, int K){
    constexpr int RPT = TM / 16;
    __shared__ float As[16][TM + 4];
    __shared__ float Bs[16][64 + 4];
    int m0 = blockIdx.x * TM, n0 = blockIdx.y * 64;
    int tid = threadIdx.x;
    int lk = tid & 15, lr = tid >> 4;
    int tx = tid & 15, ty = tid >> 4;
    float c[RPT][4] = {};
    for (int k0 = 0; k0 < K; k0 += 16){
#pragma unroll
        for (int i = 0; i < RPT; ++i)
            As[lk][lr*RPT + i] = A[(size_t)(m0 + lr*RPT + i)*lda + k0 + lk];
#pragma unroll
        for (int i = 0; i < 4; ++i)
            Bs[lk][lr*4 + i] = Bm[(size_t)(n0 + lr*4 + i)*ldb + k0 + lk];
        __syncthreads();
#pragma unroll
        for (int k = 0; k < 16; ++k){
            float b4[4];
            *(float4*)b4 = *(const float4*)&Bs[k][tx*4];
#pragma unroll
            for (int i = 0; i < RPT; ++i){
                float a = As[k][ty*RPT + i];
#pragma unroll
                for (int j = 0; j < 4; ++j) c[i][j] += a * b4[j];
            }
        }
        __syncthreads();
    }
#pragma unroll
    for (int j = 0; j < 4; ++j){
        float bb = bias ? bias[n0 + tx*4 + j] : 0.f;
#pragma unroll
        for (int i = 0; i < RPT; ++i)
            C[(size_t)(m0 + ty*RPT + i)*ldc + n0 + tx*4 + j] = c[i][j] + bb;
    }
}

// ---------------- one-time transforms fused into a single kernel ----------------
__global__ __launch_bounds__(256) void prep_all(
    const float* __restrict__ Whh, const float* __restrict__ Wo,
    const float* __restrict__ emb, const float* __restrict__ Wih,
    const float* __restrict__ elhs,
    u16* __restrict__ WhhHi, u16* __restrict__ WhhLo,
    u16* __restrict__ WoThi, u16* __restrict__ WoTlo,
    u16* __restrict__ EmbHi, u16* __restrict__ EmbLo,
    u16* __restrict__ WihLHi, u16* __restrict__ WihLLo,
    u16* __restrict__ Sh, u16* __restrict__ Sl,
    unsigned* __restrict__ zp, int nz)
{
    __shared__ float T[64][65];
    int b = blockIdx.x, tid = threadIdx.x;
    if (b < 768){
        int idx = (b*256 + tid)*4;
        float4 v = *(const float4*)&Whh[idx];
        ushort4v h,l; split_f4(v,h,l);
        *(ushort4v*)&WhhHi[idx]=h; *(ushort4v*)&WhhLo[idx]=l;
    } else if (b < 1280){
        int lb = b - 768;
        int k0 = (lb & 7)*64, n0 = (lb >> 3)*64;
#pragma unroll
        for (int i = 0; i < 16; ++i){
            int idx = tid + i*256;
            int kk = idx >> 6, nn = idx & 63;
            T[kk][nn] = Wo[(size_t)(k0+kk)*4096 + n0+nn];
        }
        __syncthreads();
#pragma unroll
        for (int i = 0; i < 16; ++i){
            int idx = tid + i*256;
            int nn = idx >> 6, kk = idx & 63;
            float v = T[kk][nn];
            u16 hi = bf16_rne(v);
            u16 lo = bf16_rne(v - __uint_as_float(((unsigned)hi) << 16));
            size_t o = (size_t)(n0+nn)*512 + k0+kk;
            WoThi[o] = hi; WoTlo[o] = lo;
        }
    } else if (b < 5376){
        int idx = ((b-1280)*256 + tid)*4;
        float4 v = *(const float4*)&emb[idx];
        ushort4v h,l; split_f4(v,h,l);
        *(ushort4v*)&EmbHi[idx]=h; *(ushort4v*)&EmbLo[idx]=l;
    } else if (b < 6912){
        int id = ((b-5376)*256 + tid)*4;
        int r = id >> 10, c = id & 1023;
        float4 v = *(const float4*)&Wih[(size_t)r*1536 + c];
        ushort4v h,l; split_f4(v,h,l);
        *(ushort4v*)&WihLHi[id]=h; *(ushort4v*)&WihLLo[id]=l;
    } else if (b < 7040){
        int idx = ((b-6912)*256 + tid)*4;
        float4 v = *(const float4*)&elhs[idx];
        ushort4v h,l; split_f4(v,h,l);
        *(ushort4v*)&Sh[idx]=h; *(ushort4v*)&Sl[idx]=l;
    } else {
        int i = ((b-7040)*256 + tid)*4;
        if (i < nz){ zp[i]=0u; zp[i+1]=0u; zp[i+2]=0u; zp[i+3]=0u; }
    }
}

// ---------------- Eproj: emb(4096x1024) @ WihL^T(1536x1024) ----------------
// Chunked LDS layout [rows][32] per 32-k chunk: staging writes linear (tid*16B),
// fragment ds_read_b128 covers the tile contiguously -> conflict-free.
// Tile 64(m) x 128(n), 4 waves 2x2, per-wave 32x64. grid (12, 64).
__global__ __launch_bounds__(256) void eproj_u16(const u16* __restrict__ Ahi, const u16* __restrict__ Alo,
                                                 const u16* __restrict__ Bhi, const u16* __restrict__ Blo,
                                                 float* __restrict__ C){
    __shared__ u16 Ah[2048], Al[2048], Bh[4096], Bl[4096];
    int n0 = blockIdx.x * 128, m0 = blockIdx.y * 64;
    int tid = threadIdx.x, lane = tid & 63, wid = tid >> 6;
    int wy = wid & 1, wx = wid >> 1;
    int l15 = lane & 15, rg = lane >> 4, lk = rg * 8;
    int ar = tid >> 2, ak8 = (tid & 3) * 8;

    const u16* gAh = Ahi + (size_t)(m0 + ar)*1024 + ak8;
    const u16* gAl = Alo + (size_t)(m0 + ar)*1024 + ak8;
    const u16* gBh0 = Bhi + (size_t)(n0 + ar)*1024 + ak8;
    const u16* gBl0 = Blo + (size_t)(n0 + ar)*1024 + ak8;
    const u16* gBh1 = gBh0 + (size_t)64*1024;
    const u16* gBl1 = gBl0 + (size_t)64*1024;

    short8v rAh = *(const short8v*)gAh;
    short8v rAl = *(const short8v*)gAl;
    short8v rBh0 = *(const short8v*)gBh0;
    short8v rBl0 = *(const short8v*)gBl0;
    short8v rBh1 = *(const short8v*)gBh1;
    short8v rBl1 = *(const short8v*)gBl1;

    f32x4 acc[2][4] = {};
    for (int k0 = 0; k0 < 1024; k0 += 32){
        __syncthreads();
        *(short8v*)&Ah[tid*8] = rAh;
        *(short8v*)&Al[tid*8] = rAl;
        *(short8v*)&Bh[tid*8] = rBh0;
        *(short8v*)&Bl[tid*8] = rBl0;
        *(short8v*)&Bh[2048 + tid*8] = rBh1;
        *(short8v*)&Bl[2048 + tid*8] = rBl1;
        __syncthreads();
        if (k0 + 32 < 1024){
            rAh  = *(const short8v*)(gAh + k0 + 32);
            rAl  = *(const short8v*)(gAl + k0 + 32);
            rBh0 = *(const short8v*)(gBh0 + k0 + 32);
            rBl0 = *(const short8v*)(gBl0 + k0 + 32);
            rBh1 = *(const short8v*)(gBh1 + k0 + 32);
            rBl1 = *(const short8v*)(gBl1 + k0 + 32);
        }
        short8v afh[2], afl[2];
        afh[0] = *(const short8v*)&Ah[(wy*32 +  0 + l15)*32 + lk];
        afh[1] = *(const short8v*)&Ah[(wy*32 + 16 + l15)*32 + lk];
        afl[0] = *(const short8v*)&Al[(wy*32 +  0 + l15)*32 + lk];
        afl[1] = *(const short8v*)&Al[(wy*32 + 16 + l15)*32 + lk];
#pragma unroll
        for (int nf = 0; nf < 4; ++nf){
            short8v bfh = *(const short8v*)&Bh[(wx*64 + nf*16 + l15)*32 + lk];
            short8v bfl = *(const short8v*)&Bl[(wx*64 + nf*16 + l15)*32 + lk];
            MFMA3(acc[0][nf], afh[0], afl[0], bfh, bfl);
            MFMA3(acc[1][nf], afh[1], afl[1], bfh, bfl);
        }
    }
    int col0 = n0 + wx*64 + l15;
#pragma unroll
    for (int mf = 0; mf < 2; ++mf)
#pragma unroll
        for (int r = 0; r < 4; ++r){
            int row = m0 + wy*32 + mf*16 + rg*4 + r;
#pragma unroll
            for (int nf = 0; nf < 4; ++nf)
                C[(size_t)row*1536 + col0 + nf*16] = acc[mf][nf][r];
        }
}

// ---------------- per-step kernels ----------------

// GRU pointwise (proven).
__global__ __launch_bounds__(256) void gru_pointwise(
    const float* __restrict__ gh, const float* __restrict__ Eproj,
    const float* __restrict__ gictx, const float* __restrict__ bhh,
    const float* __restrict__ hprev, float* __restrict__ hnext,
    u16* __restrict__ Sh, u16* __restrict__ Sl,
    const unsigned long long* __restrict__ Pprev,
    float* __restrict__ preds, int t)
{
    int tid = threadIdx.x;
    int row = blockIdx.x * 2 + (tid >> 7);
    int jj = (tid & 127) * 4;
    int w = 1;
    if (t > 0){
        w = 4095 - (int)(Pprev[row] & 0xFFFFFFFFull);
        if (w < 0) w = 0; if (w > 4095) w = 4095;
        if (jj == 0) preds[row*NSTEP + (t-1)] = (float)w;
    }
    const float* gr = gh + (size_t)row * 1536;
    const float* ep = Eproj + (size_t)w * 1536;
    const float* gc = gictx + (size_t)row * 1536;
    float4 g0 = *(const float4*)&gr[jj];
    float4 g1 = *(const float4*)&gr[512 + jj];
    float4 g2 = *(const float4*)&gr[1024 + jj];
    float4 e0 = *(const float4*)&ep[jj];
    float4 e1 = *(const float4*)&ep[512 + jj];
    float4 e2 = *(const float4*)&ep[1024 + jj];
    float4 c0 = *(const float4*)&gc[jj];
    float4 c1 = *(const float4*)&gc[512 + jj];
    float4 c2 = *(const float4*)&gc[1024 + jj];
    float4 b0 = *(const float4*)&bhh[jj];
    float4 b1 = *(const float4*)&bhh[512 + jj];
    float4 b2 = *(const float4*)&bhh[1024 + jj];
    float4 ho = *(const float4*)&hprev[(size_t)row*512 + jj];
    const float* G0 = (const float*)&g0; const float* G1 = (const float*)&g1;
    const float* G2 = (const float*)&g2;
    const float* E0 = (const float*)&e0; const float* E1 = (const float*)&e1;
    const float* E2 = (const float*)&e2;
    const float* C0 = (const float*)&c0; const float* C1 = (const float*)&c1;
    const float* C2 = (const float*)&c2;
    const float* B0 = (const float*)&b0; const float* B1 = (const float*)&b1;
    const float* B2 = (const float*)&b2;
    const float* HO = (const float*)&ho;
    float4 res;
    float* R = (float*)&res;
#pragma unroll
    for (int i = 0; i < 4; ++i){
        float gir = E0[i] + C0[i] + G0[i] + B0[i];
        float giz = E1[i] + C1[i] + G1[i] + B1[i];
        float gin = E2[i] + C2[i];
        float rr = 1.f / (1.f + expf(-gir));
        float zz = 1.f / (1.f + expf(-giz));
        float nn = tanhf(gin + rr * (G2[i] + B2[i]));
        R[i] = (1.f - zz)*nn + zz*HO[i];
    }
    size_t o = (size_t)row*512 + jj;
    *(float4*)&hnext[o] = res;
    ushort4v h4, l4; split_f4(res, h4, l4);
    *(ushort4v*)&Sh[o] = h4;
    *(ushort4v*)&Sl[o] = l4;
}

// Fused logits(t)+argmax / gh(t+1) GEMM. Round-6 shape (64x128 tile, A+B staged),
// chunked conflict-free LDS layout. grid (4, n_logits + 12).
__global__ __launch_bounds__(256) void step_mm(
    const u16* __restrict__ Ahg, const u16* __restrict__ Alg,
    const u16* __restrict__ WoHi, const u16* __restrict__ WoLo,
    const u16* __restrict__ WhhHi, const u16* __restrict__ WhhLo,
    const float* __restrict__ bo,
    float* __restrict__ logits, unsigned long long* __restrict__ Pcur,
    float* __restrict__ gh_out, int n_logits)
{
    __shared__ u16 Ah[2048], Al[2048], Bh[4096], Bl[4096];
    int m0 = blockIdx.x * 64;
    int nt = blockIdx.y;
    bool isL = nt < n_logits;
    int nbase = (isL ? nt : nt - n_logits) * 128;
    const u16* Bhg = isL ? WoHi : WhhHi;
    const u16* Blg = isL ? WoLo : WhhLo;
    int tid = threadIdx.x, lane = tid & 63, wid = tid >> 6;
    int wy = wid & 1, wx = wid >> 1;
    int l15 = lane & 15, rg = lane >> 4, lk = rg * 8;
    int ar = tid >> 2, ak8 = (tid & 3) * 8;

    const u16* gAh = Ahg + (size_t)(m0 + ar)*512 + ak8;
    const u16* gAl = Alg + (size_t)(m0 + ar)*512 + ak8;
    const u16* gBh0 = Bhg + (size_t)(nbase + ar)*512 + ak8;
    const u16* gBl0 = Blg + (size_t)(nbase + ar)*512 + ak8;
    const u16* gBh1 = gBh0 + (size_t)64*512;
    const u16* gBl1 = gBl0 + (size_t)64*512;

    short8v rAh = *(const short8v*)gAh;
    short8v rAl = *(const short8v*)gAl;
    short8v rBh0 = *(const short8v*)gBh0;
    short8v rBl0 = *(const short8v*)gBl0;
    short8v rBh1 = *(const short8v*)gBh1;
    short8v rBl1 = *(const short8v*)gBl1;

    f32x4 acc[2][4] = {};
    for (int k0 = 0; k0 < 512; k0 += 32){
        __syncthreads();
        *(short8v*)&Ah[tid*8] = rAh;
        *(short8v*)&Al[tid*8] = rAl;
        *(short8v*)&Bh[tid*8] = rBh0;
        *(short8v*)&Bl[tid*8] = rBl0;
        *(short8v*)&Bh[2048 + tid*8] = rBh1;
        *(short8v*)&Bl[2048 + tid*8] = rBl1;
        __syncthreads();
        if (k0 + 32 < 512){
            rAh  = *(const short8v*)(gAh + k0 + 32);
            rAl  = *(const short8v*)(gAl + k0 + 32);
            rBh0 = *(const short8v*)(gBh0 + k0 + 32);
            rBl0 = *(const short8v*)(gBl0 + k0 + 32);
            rBh1 = *(const short8v*)(gBh1 + k0 + 32);
            rBl1 = *(const short8v*)(gBl1 + k0 + 32);
        }
        short8v afh[2], afl[2];
        afh[0] = *(const short8v*)&Ah[(wy*32 +  0 + l15)*32 + lk];
        afh[1] = *(const short8v*)&Ah[(wy*32 + 16 + l15)*32 + lk];
        afl[0] = *(const short8v*)&Al[(wy*32 +  0 + l15)*32 + lk];
        afl[1] = *(const short8v*)&Al[(wy*32 + 16 + l15)*32 + lk];
#pragma unroll
        for (int nf = 0; nf < 4; ++nf){
            short8v bfh = *(const short8v*)&Bh[(wx*64 + nf*16 + l15)*32 + lk];
            short8v bfl = *(const short8v*)&Bl[(wx*64 + nf*16 + l15)*32 + lk];
            MFMA3(acc[0][nf], afh[0], afl[0], bfh, bfl);
            MFMA3(acc[1][nf], afh[1], afl[1], bfh, bfl);
        }
    }
    if (isL){
        float bov[4];
#pragma unroll
        for (int nf = 0; nf < 4; ++nf) bov[nf] = bo[nbase + wx*64 + nf*16 + l15];
#pragma unroll
        for (int mf = 0; mf < 2; ++mf){
#pragma unroll
            for (int r = 0; r < 4; ++r){
                int row = m0 + wy*32 + mf*16 + rg*4 + r;
                float* crow = logits + (size_t)row * (NSTEP * (size_t)V_);
                unsigned long long best = 0ULL;
#pragma unroll
                for (int nf = 0; nf < 4; ++nf){
                    int col = nbase + wx*64 + nf*16 + l15;
                    float v = acc[mf][nf][r] + bov[nf];
                    crow[col] = v;
                    unsigned long long key = ((unsigned long long)fkey(v) << 32) | (unsigned)(4095 - col);
                    if (key > best) best = key;
                }
#pragma unroll
                for (int off = 1; off < 16; off <<= 1){
                    unsigned long long o = __shfl_xor(best, off);
                    if (o > best) best = o;
                }
                if (l15 == 0) atomicMax(&Pcur[row], best);
            }
        }
    } else {
        int col0 = nbase + wx*64 + l15;
#pragma unroll
        for (int mf = 0; mf < 2; ++mf)
#pragma unroll
            for (int r = 0; r < 4; ++r){
                int row = m0 + wy*32 + mf*16 + rg*4 + r;
#pragma unroll
                for (int nf = 0; nf < 4; ++nf)
                    gh_out[(size_t)row*1536 + col0 + nf*16] = acc[mf][nf][r];
            }
    }
}

__global__ __launch_bounds__(256) void final_pred(const unsigned long long* __restrict__ P,
                                                  float* __restrict__ preds){
    int b = threadIdx.x;
    int w = 4095 - (int)(P[b] & 0xFFFFFFFFull);
    if (w < 0) w = 0; if (w > 4095) w = 4095;
    preds[b*NSTEP + (NSTEP-1)] = (float)w;
}

extern "C" void kernel_launch(void* const* d_in, const int* in_sizes, int n_in,
                              void* d_out, int out_size, void* d_ws, size_t ws_size,
                              hipStream_t stream){
    const float* elhs = (const float*)d_in[0];
    const float* enc  = (const float*)d_in[1];
    const float* emb  = (const float*)d_in[3];
    const float* W1   = (const float*)d_in[4];
    const float* W2   = (const float*)d_in[6];
    const float* W3   = (const float*)d_in[8];
    const float* W4   = (const float*)d_in[10];
    const float* Ww   = (const float*)d_in[12];
    const float* Wih  = (const float*)d_in[13];
    const float* bih  = (const float*)d_in[14];
    const float* Whh  = (const float*)d_in[15];
    const float* bhh  = (const float*)d_in[16];
    const float* Wo   = (const float*)d_in[17];
    const float* bo   = (const float*)d_in[18];

    float* out = (float*)d_out;
    float* preds = out + (size_t)B_ * NSTEP * V_;

    float* ws = (float*)d_ws;
    float* Eproj  = ws;  ws += (size_t)V_ * 1536;
    float* gictx  = ws;  ws += (size_t)B_ * 1536;
    float* ctx    = ws;  ws += B_ * H_;
    float* scores = ws;  ws += B_ * S_;
    float* t1     = ws;  ws += 512;
    float* t2     = ws;  ws += 512;
    float* weff   = ws;  ws += 512;
    float* Hf     = ws;  ws += 2 * B_ * H_;
    float* ghbuf  = ws;  ws += B_ * 1536;
    u16* WoT_hi = (u16*)ws;  ws += (size_t)V_ * 512 / 2;
    u16* WoT_lo = (u16*)ws;  ws += (size_t)V_ * 512 / 2;
    u16* WhhHi  = (u16*)ws;  ws += 1536 * 512 / 2;
    u16* WhhLo  = (u16*)ws;  ws += 1536 * 512 / 2;
    u16* Sh     = (u16*)ws;  ws += B_ * H_ / 2;
    u16* Sl     = (u16*)ws;  ws += B_ * H_ / 2;
    unsigned long long* P = (unsigned long long*)ws;   // 27*256 u64

    // big one-time splits parked in d_out head (consumed by eproj before logits writes)
    u16* EmbHi  = (u16*)d_out;
    u16* EmbLo  = EmbHi + (size_t)V_*1024;
    u16* WihLHi = EmbLo + (size_t)V_*1024;
    u16* WihLLo = WihLHi + (size_t)1536*1024;

    prep_all<<<7054, 256, 0, stream>>>(Whh, Wo, emb, Wih, elhs,
                                       WhhHi, WhhLo, WoT_hi, WoT_lo,
                                       EmbHi, EmbLo, WihLHi, WihLLo,
                                       Sh, Sl, (unsigned*)P, NSTEP*256*2);

    matvec512<<<512, 64, 0, stream>>>(W4, Ww, t1);
    matvec512<<<512, 64, 0, stream>>>(W3, t1, t2);
    matvec512<<<512, 64, 0, stream>>>(W2, t2, t1);
    matvec512<<<512, 64, 0, stream>>>(W1, t1, weff);
    score_kernel<<<(B_*S_)/4, 256, 0, stream>>>(enc, weff, scores);
    softmax_ctx<<<B_, 512, 0, stream>>>(enc, scores, ctx);
    { dim3 g(B_/32, 1536/64);
      gemm_abt<32><<<g, 256, 0, stream>>>(ctx, 512, Wih + 1024, 1536, bih, gictx, 1536, 512); }
    { dim3 g(1536/128, V_/64);
      eproj_u16<<<g, 256, 0, stream>>>(EmbHi, EmbLo, WihLHi, WihLLo, Eproj); }

    // gh_0 = h0 @ Whh^T
    { dim3 g(4, 12);
      step_mm<<<g, 256, 0, stream>>>(Sh, Sl, WoT_hi, WoT_lo, WhhHi, WhhLo, bo,
                                     out, P, ghbuf, 0); }

    for (int t = 0; t < NSTEP; ++t){
        const float* hr = (t == 0) ? elhs : (Hf + (size_t)((t-1) & 1) * (B_*H_));
        float*       hw = Hf + (size_t)(t & 1) * (B_*H_);
        const unsigned long long* Pprev = P + (size_t)(t > 0 ? t-1 : 0) * 256;
        gru_pointwise<<<128, 256, 0, stream>>>(ghbuf, Eproj, gictx, bhh, hr, hw,
                                               Sh, Sl, Pprev, preds, t);
        dim3 g(4, 32 + 12);
        step_mm<<<g, 256, 0, stream>>>(Sh, Sl, WoT_hi, WoT_lo, WhhHi, WhhLo, bo,
                                       out + (size_t)t * V_, P + (size_t)t*256, ghbuf, 32);
    }
    final_pred<<<1, 256, 0, stream>>>(P + (size_t)(NSTEP-1)*256, preds);
}

// Round 10
// 746.547 us; speedup vs baseline: 2.2140x; 1.0224x over previous
//
#include <hip/hip_runtime.h>

#define B_ 256
#define S_ 80
#define H_ 512
#define V_ 4096
#define NSTEP 27

typedef unsigned short u16;
typedef __attribute__((ext_vector_type(8))) short short8v;
typedef __attribute__((ext_vector_type(4))) float f32x4;
typedef __attribute__((ext_vector_type(4))) unsigned short ushort4v;

#define MFMA_(a,b,c) __builtin_amdgcn_mfma_f32_16x16x32_bf16(a,b,c,0,0,0)
#define MFMA3(acc, ah, al, bh, bl) do{ acc = MFMA_(ah,bh,acc); acc = MFMA_(ah,bl,acc); acc = MFMA_(al,bh,acc);}while(0)

__device__ __forceinline__ unsigned fkey(float v){
    unsigned u = __float_as_uint(v);
    return (u & 0x80000000u) ? ~u : (u | 0x80000000u);
}
__device__ __forceinline__ u16 bf16_rne(float f){
    unsigned u = __float_as_uint(f);
    return (u16)((u + 0x7FFFu + ((u >> 16) & 1u)) >> 16);
}
__device__ __forceinline__ void split_f4(float4 v, ushort4v& hi, ushort4v& lo){
    float arr[4] = {v.x, v.y, v.z, v.w};
    ushort4v h, l;
#pragma unroll
    for (int i = 0; i < 4; ++i){
        u16 hb = bf16_rne(arr[i]);
        h[i] = hb;
        l[i] = bf16_rne(arr[i] - __uint_as_float(((unsigned)hb) << 16));
    }
    hi = h; lo = l;
}

// ---------------- front ----------------
__global__ __launch_bounds__(64) void matvec512(const float* __restrict__ W,
                                                const float* __restrict__ v,
                                                float* __restrict__ out){
    int row = blockIdx.x, lane = threadIdx.x;
    const float* wr = W + row * 512;
    float s = 0.f;
#pragma unroll
    for (int i = 0; i < 8; ++i) s += wr[lane + 64*i] * v[lane + 64*i];
#pragma unroll
    for (int off = 32; off; off >>= 1) s += __shfl_xor(s, off);
    if (lane == 0) out[row] = s;
}

// scores + softmax + context fused (scores arithmetic identical to prior split version)
__global__ __launch_bounds__(512) void attn_ctx(const float* __restrict__ enc,
                                                const float* __restrict__ weff,
                                                float* __restrict__ ctx){
    __shared__ float att[S_];
    int b = blockIdx.x, tid = threadIdx.x;
    int wv = tid >> 6, lane = tid & 63;
    float w8[8];
#pragma unroll
    for (int i = 0; i < 8; ++i) w8[i] = weff[lane + 64*i];
    const float* eb = enc + (size_t)b * (S_*H_);
    for (int s = wv; s < S_; s += 8){
        const float* e = eb + s*512;
        float acc = 0.f;
#pragma unroll
        for (int i = 0; i < 8; ++i) acc += e[lane + 64*i] * w8[i];
#pragma unroll
        for (int off = 32; off; off >>= 1) acc += __shfl_xor(acc, off);
        if (lane == 0) att[s] = acc;
    }
    __syncthreads();
    if (tid == 0){
        float mx = att[0];
        for (int s = 1; s < S_; ++s) mx = fmaxf(mx, att[s]);
        float sum = 0.f;
        for (int s = 0; s < S_; ++s){ float e = expf(att[s] - mx); att[s] = e; sum += e; }
        float inv = 1.f / sum;
        for (int s = 0; s < S_; ++s) att[s] *= inv;
    }
    __syncthreads();
    float a = 0.f;
    for (int s = 0; s < S_; ++s) a += att[s] * eb[s*512 + tid];
    ctx[b*512 + tid] = a;
}

template<int TM>
__global__ __launch_bounds__(256) void gemm_abt(const float* __restrict__ A, int lda,
                                                const float* __restrict__ Bm, int ldb,
                                                const float* __restrict__ bias,
                                                float* __restrict__ C, int ldc, int K){
    constexpr int RPT = TM / 16;
    __shared__ float As[16][TM + 4];
    __shared__ float Bs[16][64 + 4];
    int m0 = blockIdx.x * TM, n0 = blockIdx.y * 64;
    int tid = threadIdx.x;
    int lk = tid & 15, lr = tid >> 4;
    int tx = tid & 15, ty = tid >> 4;
    float c[RPT][4] = {};
    for (int k0 = 0; k0 < K; k0 += 16){
#pragma unroll
        for (int i = 0; i < RPT; ++i)
            As[lk][lr*RPT + i] = A[(size_t)(m0 + lr*RPT + i)*lda + k0 + lk];
#pragma unroll
        for (int i = 0; i < 4; ++i)
            Bs[lk][lr*4 + i] = Bm[(size_t)(n0 + lr*4 + i)*ldb + k0 + lk];
        __syncthreads();
#pragma unroll
        for (int k = 0; k < 16; ++k){
            float b4[4];
            *(float4*)b4 = *(const float4*)&Bs[k][tx*4];
#pragma unroll
            for (int i = 0; i < RPT; ++i){
                float a = As[k][ty*RPT + i];
#pragma unroll
                for (int j = 0; j < 4; ++j) c[i][j] += a * b4[j];
            }
        }
        __syncthreads();
    }
#pragma unroll
    for (int j = 0; j < 4; ++j){
        float bb = bias ? bias[n0 + tx*4 + j] : 0.f;
#pragma unroll
        for (int i = 0; i < RPT; ++i)
            C[(size_t)(m0 + ty*RPT + i)*ldc + n0 + tx*4 + j] = c[i][j] + bb;
    }
}

// ---------------- one-time transforms fused into a single kernel ----------------
__global__ __launch_bounds__(256) void prep_all(
    const float* __restrict__ Whh, const float* __restrict__ Wo,
    const float* __restrict__ emb, const float* __restrict__ Wih,
    const float* __restrict__ elhs,
    u16* __restrict__ WhhHi, u16* __restrict__ WhhLo,
    u16* __restrict__ WoThi, u16* __restrict__ WoTlo,
    u16* __restrict__ EmbHi, u16* __restrict__ EmbLo,
    u16* __restrict__ WihLHi, u16* __restrict__ WihLLo,
    u16* __restrict__ Sh, u16* __restrict__ Sl,
    unsigned* __restrict__ zp, int nz)
{
    __shared__ float T[64][65];
    int b = blockIdx.x, tid = threadIdx.x;
    if (b < 768){
        int idx = (b*256 + tid)*4;
        float4 v = *(const float4*)&Whh[idx];
        ushort4v h,l; split_f4(v,h,l);
        *(ushort4v*)&WhhHi[idx]=h; *(ushort4v*)&WhhLo[idx]=l;
    } else if (b < 1280){
        int lb = b - 768;
        int k0 = (lb & 7)*64, n0 = (lb >> 3)*64;
#pragma unroll
        for (int i = 0; i < 16; ++i){
            int idx = tid + i*256;
            int kk = idx >> 6, nn = idx & 63;
            T[kk][nn] = Wo[(size_t)(k0+kk)*4096 + n0+nn];
        }
        __syncthreads();
#pragma unroll
        for (int i = 0; i < 16; ++i){
            int idx = tid + i*256;
            int nn = idx >> 6, kk = idx & 63;
            float v = T[kk][nn];
            u16 hi = bf16_rne(v);
            u16 lo = bf16_rne(v - __uint_as_float(((unsigned)hi) << 16));
            size_t o = (size_t)(n0+nn)*512 + k0+kk;
            WoThi[o] = hi; WoTlo[o] = lo;
        }
    } else if (b < 5376){
        int idx = ((b-1280)*256 + tid)*4;
        float4 v = *(const float4*)&emb[idx];
        ushort4v h,l; split_f4(v,h,l);
        *(ushort4v*)&EmbHi[idx]=h; *(ushort4v*)&EmbLo[idx]=l;
    } else if (b < 6912){
        int id = ((b-5376)*256 + tid)*4;
        int r = id >> 10, c = id & 1023;
        float4 v = *(const float4*)&Wih[(size_t)r*1536 + c];
        ushort4v h,l; split_f4(v,h,l);
        *(ushort4v*)&WihLHi[id]=h; *(ushort4v*)&WihLLo[id]=l;
    } else if (b < 7040){
        int idx = ((b-6912)*256 + tid)*4;
        float4 v = *(const float4*)&elhs[idx];
        ushort4v h,l; split_f4(v,h,l);
        *(ushort4v*)&Sh[idx]=h; *(ushort4v*)&Sl[idx]=l;
    } else {
        int i = ((b-7040)*256 + tid)*4;
        if (i < nz){ zp[i]=0u; zp[i+1]=0u; zp[i+2]=0u; zp[i+3]=0u; }
    }
}

// ---------------- Eproj (proven round-9 chunked version) ----------------
__global__ __launch_bounds__(256) void eproj_u16(const u16* __restrict__ Ahi, const u16* __restrict__ Alo,
                                                 const u16* __restrict__ Bhi, const u16* __restrict__ Blo,
                                                 float* __restrict__ C){
    __shared__ u16 Ah[2048], Al[2048], Bh[4096], Bl[4096];
    int n0 = blockIdx.x * 128, m0 = blockIdx.y * 64;
    int tid = threadIdx.x, lane = tid & 63, wid = tid >> 6;
    int wy = wid & 1, wx = wid >> 1;
    int l15 = lane & 15, rg = lane >> 4, lk = rg * 8;
    int ar = tid >> 2, ak8 = (tid & 3) * 8;

    const u16* gAh = Ahi + (size_t)(m0 + ar)*1024 + ak8;
    const u16* gAl = Alo + (size_t)(m0 + ar)*1024 + ak8;
    const u16* gBh0 = Bhi + (size_t)(n0 + ar)*1024 + ak8;
    const u16* gBl0 = Blo + (size_t)(n0 + ar)*1024 + ak8;
    const u16* gBh1 = gBh0 + (size_t)64*1024;
    const u16* gBl1 = gBl0 + (size_t)64*1024;

    short8v rAh = *(const short8v*)gAh;
    short8v rAl = *(const short8v*)gAl;
    short8v rBh0 = *(const short8v*)gBh0;
    short8v rBl0 = *(const short8v*)gBl0;
    short8v rBh1 = *(const short8v*)gBh1;
    short8v rBl1 = *(const short8v*)gBl1;

    f32x4 acc[2][4] = {};
    for (int k0 = 0; k0 < 1024; k0 += 32){
        __syncthreads();
        *(short8v*)&Ah[tid*8] = rAh;
        *(short8v*)&Al[tid*8] = rAl;
        *(short8v*)&Bh[tid*8] = rBh0;
        *(short8v*)&Bl[tid*8] = rBl0;
        *(short8v*)&Bh[2048 + tid*8] = rBh1;
        *(short8v*)&Bl[2048 + tid*8] = rBl1;
        __syncthreads();
        if (k0 + 32 < 1024){
            rAh  = *(const short8v*)(gAh + k0 + 32);
            rAl  = *(const short8v*)(gAl + k0 + 32);
            rBh0 = *(const short8v*)(gBh0 + k0 + 32);
            rBl0 = *(const short8v*)(gBl0 + k0 + 32);
            rBh1 = *(const short8v*)(gBh1 + k0 + 32);
            rBl1 = *(const short8v*)(gBl1 + k0 + 32);
        }
        short8v afh[2], afl[2];
        afh[0] = *(const short8v*)&Ah[(wy*32 +  0 + l15)*32 + lk];
        afh[1] = *(const short8v*)&Ah[(wy*32 + 16 + l15)*32 + lk];
        afl[0] = *(const short8v*)&Al[(wy*32 +  0 + l15)*32 + lk];
        afl[1] = *(const short8v*)&Al[(wy*32 + 16 + l15)*32 + lk];
#pragma unroll
        for (int nf = 0; nf < 4; ++nf){
            short8v bfh = *(const short8v*)&Bh[(wx*64 + nf*16 + l15)*32 + lk];
            short8v bfl = *(const short8v*)&Bl[(wx*64 + nf*16 + l15)*32 + lk];
            MFMA3(acc[0][nf], afh[0], afl[0], bfh, bfl);
            MFMA3(acc[1][nf], afh[1], afl[1], bfh, bfl);
        }
    }
    int col0 = n0 + wx*64 + l15;
#pragma unroll
    for (int mf = 0; mf < 2; ++mf)
#pragma unroll
        for (int r = 0; r < 4; ++r){
            int row = m0 + wy*32 + mf*16 + rg*4 + r;
#pragma unroll
            for (int nf = 0; nf < 4; ++nf)
                C[(size_t)row*1536 + col0 + nf*16] = acc[mf][nf][r];
        }
}

// ---------------- per-step kernels ----------------

// GRU pointwise: 256 blocks x 128 threads (1 row/block) for latency spread.
__global__ __launch_bounds__(128) void gru_pointwise(
    const float* __restrict__ gh, const float* __restrict__ Eproj,
    const float* __restrict__ gictx, const float* __restrict__ bhh,
    const float* __restrict__ hprev, float* __restrict__ hnext,
    u16* __restrict__ Sh, u16* __restrict__ Sl,
    const unsigned long long* __restrict__ Pprev,
    float* __restrict__ preds, int t)
{
    int tid = threadIdx.x;
    int row = blockIdx.x;
    int jj = tid * 4;
    int w = 1;
    if (t > 0){
        w = 4095 - (int)(Pprev[row] & 0xFFFFFFFFull);
        if (w < 0) w = 0; if (w > 4095) w = 4095;
        if (tid == 0) preds[row*NSTEP + (t-1)] = (float)w;
    }
    const float* gr = gh + (size_t)row * 1536;
    const float* ep = Eproj + (size_t)w * 1536;
    const float* gc = gictx + (size_t)row * 1536;
    float4 g0 = *(const float4*)&gr[jj];
    float4 g1 = *(const float4*)&gr[512 + jj];
    float4 g2 = *(const float4*)&gr[1024 + jj];
    float4 e0 = *(const float4*)&ep[jj];
    float4 e1 = *(const float4*)&ep[512 + jj];
    float4 e2 = *(const float4*)&ep[1024 + jj];
    float4 c0 = *(const float4*)&gc[jj];
    float4 c1 = *(const float4*)&gc[512 + jj];
    float4 c2 = *(const float4*)&gc[1024 + jj];
    float4 b0 = *(const float4*)&bhh[jj];
    float4 b1 = *(const float4*)&bhh[512 + jj];
    float4 b2 = *(const float4*)&bhh[1024 + jj];
    float4 ho = *(const float4*)&hprev[(size_t)row*512 + jj];
    const float* G0 = (const float*)&g0; const float* G1 = (const float*)&g1;
    const float* G2 = (const float*)&g2;
    const float* E0 = (const float*)&e0; const float* E1 = (const float*)&e1;
    const float* E2 = (const float*)&e2;
    const float* C0 = (const float*)&c0; const float* C1 = (const float*)&c1;
    const float* C2 = (const float*)&c2;
    const float* B0 = (const float*)&b0; const float* B1 = (const float*)&b1;
    const float* B2 = (const float*)&b2;
    const float* HO = (const float*)&ho;
    float4 res;
    float* R = (float*)&res;
#pragma unroll
    for (int i = 0; i < 4; ++i){
        float gir = E0[i] + C0[i] + G0[i] + B0[i];
        float giz = E1[i] + C1[i] + G1[i] + B1[i];
        float gin = E2[i] + C2[i];
        float rr = 1.f / (1.f + expf(-gir));
        float zz = 1.f / (1.f + expf(-giz));
        float nn = tanhf(gin + rr * (G2[i] + B2[i]));
        R[i] = (1.f - zz)*nn + zz*HO[i];
    }
    size_t o = (size_t)row*512 + jj;
    *(float4*)&hnext[o] = res;
    ushort4v h4, l4; split_f4(res, h4, l4);
    *(ushort4v*)&Sh[o] = h4;
    *(ushort4v*)&Sl[o] = l4;
}

// Fused logits(t)+argmax / gh(t+1) GEMM. 64x64 tile, 4 waves 2x2 (32x32 each).
// Chunked LDS, double-buffered (1 barrier/iter), 2-chunk-deep register prefetch.
// grid (4, n_logits + 24); nt < n_logits -> logits 64-col tile; else gh tile.
__global__ __launch_bounds__(256) void step_mm(
    const u16* __restrict__ Ahg, const u16* __restrict__ Alg,
    const u16* __restrict__ WoHi, const u16* __restrict__ WoLo,
    const u16* __restrict__ WhhHi, const u16* __restrict__ WhhLo,
    const float* __restrict__ bo,
    float* __restrict__ logits, unsigned long long* __restrict__ Pcur,
    float* __restrict__ gh_out, int n_logits)
{
    __shared__ u16 Ah[2][2048], Al[2][2048], Bh[2][2048], Bl[2][2048];  // 32 KB
    int m0 = blockIdx.x * 64;
    int nt = blockIdx.y;
    bool isL = nt < n_logits;
    int nbase = (isL ? nt : nt - n_logits) * 64;
    const u16* Bhg = isL ? WoHi : WhhHi;
    const u16* Blg = isL ? WoLo : WhhLo;
    int tid = threadIdx.x, lane = tid & 63, wid = tid >> 6;
    int wy = wid & 1, wx = wid >> 1;
    int l15 = lane & 15, rg = lane >> 4, lk = rg * 8;
    int sr = tid >> 2, sk8 = (tid & 3) * 8;

    const u16* gAh = Ahg + (size_t)(m0 + sr)*512 + sk8;
    const u16* gAl = Alg + (size_t)(m0 + sr)*512 + sk8;
    const u16* gBh = Bhg + (size_t)(nbase + sr)*512 + sk8;
    const u16* gBl = Blg + (size_t)(nbase + sr)*512 + sk8;

    // chunk 0 -> buf 0; prefetch chunks 1,2 into regs
    *(short8v*)&Ah[0][tid*8] = *(const short8v*)gAh;
    *(short8v*)&Al[0][tid*8] = *(const short8v*)gAl;
    *(short8v*)&Bh[0][tid*8] = *(const short8v*)gBh;
    *(short8v*)&Bl[0][tid*8] = *(const short8v*)gBl;
    short8v r1a = *(const short8v*)(gAh + 32), r1b = *(const short8v*)(gAl + 32);
    short8v r1c = *(const short8v*)(gBh + 32), r1d = *(const short8v*)(gBl + 32);
    short8v r2a = *(const short8v*)(gAh + 64), r2b = *(const short8v*)(gAl + 64);
    short8v r2c = *(const short8v*)(gBh + 64), r2d = *(const short8v*)(gBl + 64);
    __syncthreads();

    f32x4 acc[2][2] = {};
    int p = 0;
    for (int k0 = 0; k0 < 512; k0 += 32){
        if (k0 + 32 < 512){
            // write chunk k0+32 into the other buffer
            *(short8v*)&Ah[p^1][tid*8] = r1a;
            *(short8v*)&Al[p^1][tid*8] = r1b;
            *(short8v*)&Bh[p^1][tid*8] = r1c;
            *(short8v*)&Bl[p^1][tid*8] = r1d;
            r1a = r2a; r1b = r2b; r1c = r2c; r1d = r2d;
            if (k0 + 96 < 512){
                r2a = *(const short8v*)(gAh + k0 + 96);
                r2b = *(const short8v*)(gAl + k0 + 96);
                r2c = *(const short8v*)(gBh + k0 + 96);
                r2d = *(const short8v*)(gBl + k0 + 96);
            }
        }
        short8v afh0 = *(const short8v*)&Ah[p][(wy*32 +  0 + l15)*32 + lk];
        short8v afh1 = *(const short8v*)&Ah[p][(wy*32 + 16 + l15)*32 + lk];
        short8v afl0 = *(const short8v*)&Al[p][(wy*32 +  0 + l15)*32 + lk];
        short8v afl1 = *(const short8v*)&Al[p][(wy*32 + 16 + l15)*32 + lk];
        short8v bfh0 = *(const short8v*)&Bh[p][(wx*32 +  0 + l15)*32 + lk];
        short8v bfh1 = *(const short8v*)&Bh[p][(wx*32 + 16 + l15)*32 + lk];
        short8v bfl0 = *(const short8v*)&Bl[p][(wx*32 +  0 + l15)*32 + lk];
        short8v bfl1 = *(const short8v*)&Bl[p][(wx*32 + 16 + l15)*32 + lk];
        MFMA3(acc[0][0], afh0, afl0, bfh0, bfl0);
        MFMA3(acc[0][1], afh0, afl0, bfh1, bfl1);
        MFMA3(acc[1][0], afh1, afl1, bfh0, bfl0);
        MFMA3(acc[1][1], afh1, afl1, bfh1, bfl1);
        __syncthreads();
        p ^= 1;
    }

    int col0 = nbase + wx*32 + l15;
    if (isL){
        float bo0 = bo[col0], bo1 = bo[col0 + 16];
#pragma unroll
        for (int mf = 0; mf < 2; ++mf){
#pragma unroll
            for (int r = 0; r < 4; ++r){
                int row = m0 + wy*32 + mf*16 + rg*4 + r;
                float v0 = acc[mf][0][r] + bo0;
                float v1 = acc[mf][1][r] + bo1;
                float* crow = logits + (size_t)row * (NSTEP * (size_t)V_);
                crow[col0]      = v0;
                crow[col0 + 16] = v1;
                unsigned long long k0_ = ((unsigned long long)fkey(v0) << 32) | (unsigned)(4095 - col0);
                unsigned long long k1_ = ((unsigned long long)fkey(v1) << 32) | (unsigned)(4095 - (col0+16));
                unsigned long long best = k0_ > k1_ ? k0_ : k1_;
#pragma unroll
                for (int off = 1; off < 16; off <<= 1){
                    unsigned long long o = __shfl_xor(best, off);
                    if (o > best) best = o;
                }
                if (l15 == 0) atomicMax(&Pcur[row], best);
            }
        }
    } else {
#pragma unroll
        for (int mf = 0; mf < 2; ++mf)
#pragma unroll
            for (int r = 0; r < 4; ++r){
                int row = m0 + wy*32 + mf*16 + rg*4 + r;
                gh_out[(size_t)row*1536 + col0]      = acc[mf][0][r];
                gh_out[(size_t)row*1536 + col0 + 16] = acc[mf][1][r];
            }
    }
}

__global__ __launch_bounds__(256) void final_pred(const unsigned long long* __restrict__ P,
                                                  float* __restrict__ preds){
    int b = threadIdx.x;
    int w = 4095 - (int)(P[b] & 0xFFFFFFFFull);
    if (w < 0) w = 0; if (w > 4095) w = 4095;
    preds[b*NSTEP + (NSTEP-1)] = (float)w;
}

extern "C" void kernel_launch(void* const* d_in, const int* in_sizes, int n_in,
                              void* d_out, int out_size, void* d_ws, size_t ws_size,
                              hipStream_t stream){
    const float* elhs = (const float*)d_in[0];
    const float* enc  = (const float*)d_in[1];
    const float* emb  = (const float*)d_in[3];
    const float* W1   = (const float*)d_in[4];
    const float* W2   = (const float*)d_in[6];
    const float* W3   = (const float*)d_in[8];
    const float* W4   = (const float*)d_in[10];
    const float* Ww   = (const float*)d_in[12];
    const float* Wih  = (const float*)d_in[13];
    const float* bih  = (const float*)d_in[14];
    const float* Whh  = (const float*)d_in[15];
    const float* bhh  = (const float*)d_in[16];
    const float* Wo   = (const float*)d_in[17];
    const float* bo   = (const float*)d_in[18];

    float* out = (float*)d_out;
    float* preds = out + (size_t)B_ * NSTEP * V_;

    float* ws = (float*)d_ws;
    float* Eproj  = ws;  ws += (size_t)V_ * 1536;
    float* gictx  = ws;  ws += (size_t)B_ * 1536;
    float* ctx    = ws;  ws += B_ * H_;
    float* t1     = ws;  ws += 512;
    float* t2     = ws;  ws += 512;
    float* weff   = ws;  ws += 512;
    float* Hf     = ws;  ws += 2 * B_ * H_;
    float* ghbuf  = ws;  ws += B_ * 1536;
    u16* WoT_hi = (u16*)ws;  ws += (size_t)V_ * 512 / 2;
    u16* WoT_lo = (u16*)ws;  ws += (size_t)V_ * 512 / 2;
    u16* WhhHi  = (u16*)ws;  ws += 1536 * 512 / 2;
    u16* WhhLo  = (u16*)ws;  ws += 1536 * 512 / 2;
    u16* Sh     = (u16*)ws;  ws += B_ * H_ / 2;
    u16* Sl     = (u16*)ws;  ws += B_ * H_ / 2;
    unsigned long long* P = (unsigned long long*)ws;   // 27*256 u64

    // big one-time splits parked in d_out head (consumed by eproj before logits writes)
    u16* EmbHi  = (u16*)d_out;
    u16* EmbLo  = EmbHi + (size_t)V_*1024;
    u16* WihLHi = EmbLo + (size_t)V_*1024;
    u16* WihLLo = WihLHi + (size_t)1536*1024;

    prep_all<<<7054, 256, 0, stream>>>(Whh, Wo, emb, Wih, elhs,
                                       WhhHi, WhhLo, WoT_hi, WoT_lo,
                                       EmbHi, EmbLo, WihLHi, WihLLo,
                                       Sh, Sl, (unsigned*)P, NSTEP*256*2);

    matvec512<<<512, 64, 0, stream>>>(W4, Ww, t1);
    matvec512<<<512, 64, 0, stream>>>(W3, t1, t2);
    matvec512<<<512, 64, 0, stream>>>(W2, t2, t1);
    matvec512<<<512, 64, 0, stream>>>(W1, t1, weff);
    attn_ctx<<<B_, 512, 0, stream>>>(enc, weff, ctx);
    { dim3 g(B_/32, 1536/64);
      gemm_abt<32><<<g, 256, 0, stream>>>(ctx, 512, Wih + 1024, 1536, bih, gictx, 1536, 512); }
    { dim3 g(1536/128, V_/64);
      eproj_u16<<<g, 256, 0, stream>>>(EmbHi, EmbLo, WihLHi, WihLLo, Eproj); }

    // gh_0 = h0 @ Whh^T
    { dim3 g(4, 24);
      step_mm<<<g, 256, 0, stream>>>(Sh, Sl, WoT_hi, WoT_lo, WhhHi, WhhLo, bo,
                                     out, P, ghbuf, 0); }

    for (int t = 0; t < NSTEP; ++t){
        const float* hr = (t == 0) ? elhs : (Hf + (size_t)((t-1) & 1) * (B_*H_));
        float*       hw = Hf + (size_t)(t & 1) * (B_*H_);
        const unsigned long long* Pprev = P + (size_t)(t > 0 ? t-1 : 0) * 256;
        gru_pointwise<<<256, 128, 0, stream>>>(ghbuf, Eproj, gictx, bhh, hr, hw,
                                               Sh, Sl, Pprev, preds, t);
        dim3 g(4, 64 + 24);
        step_mm<<<g, 256, 0, stream>>>(Sh, Sl, WoT_hi, WoT_lo, WhhHi, WhhLo, bo,
                                       out + (size_t)t * V_, P + (size_t)t*256, ghbuf, 64);
    }
    final_pred<<<1, 256, 0, stream>>>(P + (size_t)(NSTEP-1)*256, preds);
}